// Round 1
// baseline (324.130 us; speedup 1.0000x reference)
//
#include <hip/hip_runtime.h>

#define N_NODES 10000
#define E_RAW   320000
#define E_TOT   330000
#define D_IN    256
#define HID     128
#define HEADS   4
#define F1      512   // HEADS*HID
#define D_OUT   256
#define SLOPE   0.2f
#define NEG_INF -3.0e38f

// ---------------- CSR build ----------------

__global__ __launch_bounds__(256) void k_hist(const int* __restrict__ ei, int* __restrict__ deg) {
    int e = blockIdx.x * 256 + threadIdx.x;
    if (e < E_TOT) {
        int dst = (e < E_RAW) ? ei[E_RAW + e] : (e - E_RAW);
        atomicAdd(&deg[dst], 1);
    }
}

__global__ __launch_bounds__(256) void k_scan(const int* __restrict__ deg,
                                              int* __restrict__ row_start,
                                              int* __restrict__ cursor) {
    __shared__ int buf[256];
    __shared__ int carry_s;
    int tid = threadIdx.x;
    if (tid == 0) carry_s = 0;
    __syncthreads();
    for (int base = 0; base < N_NODES; base += 256) {
        int idx = base + tid;
        int v = (idx < N_NODES) ? deg[idx] : 0;
        buf[tid] = v;
        __syncthreads();
        for (int off = 1; off < 256; off <<= 1) {
            int t = (tid >= off) ? buf[tid - off] : 0;
            __syncthreads();
            buf[tid] += t;
            __syncthreads();
        }
        int incl = buf[tid];
        int excl = incl - v;
        int carry = carry_s;
        if (idx < N_NODES) {
            row_start[idx] = carry + excl;
            cursor[idx]    = carry + excl;
        }
        __syncthreads();
        if (tid == 255) carry_s = carry + incl;
        __syncthreads();
    }
    if (tid == 0) row_start[N_NODES] = E_TOT;
}

__global__ __launch_bounds__(256) void k_scatter(const int* __restrict__ ei,
                                                 int* __restrict__ cursor,
                                                 int* __restrict__ csr_src) {
    int e = blockIdx.x * 256 + threadIdx.x;
    if (e < E_TOT) {
        int src = (e < E_RAW) ? ei[e] : (e - E_RAW);
        int dst = (e < E_RAW) ? ei[E_RAW + e] : (e - E_RAW);
        int pos = atomicAdd(&cursor[dst], 1);
        csr_src[pos] = src;
    }
}

// ---------------- f32 tiled GEMM: C[M,N] = A[M,K] @ B[K,N] ----------------
// BM=64, BN=64, BK=16, 256 threads, 4x4 per thread.

__global__ __launch_bounds__(256) void k_gemm(const float* __restrict__ A,
                                              const float* __restrict__ B,
                                              float* __restrict__ C,
                                              int M, int N, int K) {
    __shared__ float As[16][64];   // [k][m] transposed
    __shared__ float Bs[16][64];   // [k][n]
    int tid = threadIdx.x;
    int tx = tid & 15;             // 0..15 (col group)
    int ty = tid >> 4;             // 0..15 (row group)
    int block_row = blockIdx.y * 64;
    int block_col = blockIdx.x * 64;

    float acc[4][4];
    #pragma unroll
    for (int i = 0; i < 4; i++)
        #pragma unroll
        for (int j = 0; j < 4; j++) acc[i][j] = 0.f;

    int a_row = tid >> 2;          // 0..63
    int a_col = (tid & 3) * 4;     // 0,4,8,12
    int b_row = tid >> 4;          // 0..15
    int b_col = (tid & 15) * 4;    // 0..60

    for (int k0 = 0; k0 < K; k0 += 16) {
        int gr = block_row + a_row;
        float4 av;
        if (gr < M) av = *(const float4*)&A[(size_t)gr * K + k0 + a_col];
        else        av = make_float4(0.f, 0.f, 0.f, 0.f);
        As[a_col + 0][a_row] = av.x;
        As[a_col + 1][a_row] = av.y;
        As[a_col + 2][a_row] = av.z;
        As[a_col + 3][a_row] = av.w;
        float4 bv = *(const float4*)&B[(size_t)(k0 + b_row) * N + block_col + b_col];
        *(float4*)&Bs[b_row][b_col] = bv;
        __syncthreads();
        #pragma unroll
        for (int k = 0; k < 16; k++) {
            float a[4], b[4];
            *(float4*)a = *(const float4*)&As[k][ty * 4];
            *(float4*)b = *(const float4*)&Bs[k][tx * 4];
            #pragma unroll
            for (int i = 0; i < 4; i++)
                #pragma unroll
                for (int j = 0; j < 4; j++)
                    acc[i][j] += a[i] * b[j];
        }
        __syncthreads();
    }
    #pragma unroll
    for (int i = 0; i < 4; i++) {
        int r = block_row + ty * 4 + i;
        if (r < M) {
            float4 v = make_float4(acc[i][0], acc[i][1], acc[i][2], acc[i][3]);
            *(float4*)&C[(size_t)r * N + block_col + tx * 4] = v;
        }
    }
}

// ---------------- attention vectors ----------------

// layer 1: per node, per head h: as1[n,h] = dot(h1[n, h*128: ], a1_src[h]); same for dst
__global__ __launch_bounds__(256) void k_attn_vec1(const float* __restrict__ h1,
                                                   const float* __restrict__ a1s,
                                                   const float* __restrict__ a1d,
                                                   float* __restrict__ as1,
                                                   float* __restrict__ ad1) {
    int node = blockIdx.x;
    int tid = threadIdx.x;
    int wave = tid >> 6;   // = head
    int lane = tid & 63;
    const float* hr = h1 + (size_t)node * F1 + wave * HID;
    const float* svp = a1s + wave * HID;
    const float* dvp = a1d + wave * HID;
    float h0 = hr[lane], h1v = hr[lane + 64];
    float s_ = h0 * svp[lane] + h1v * svp[lane + 64];
    float d_ = h0 * dvp[lane] + h1v * dvp[lane + 64];
    #pragma unroll
    for (int off = 32; off >= 1; off >>= 1) {
        s_ += __shfl_xor(s_, off, 64);
        d_ += __shfl_xor(d_, off, 64);
    }
    if (lane == 0) {
        as1[node * 4 + wave] = s_;
        ad1[node * 4 + wave] = d_;
    }
}

// layer 2: single head over 256 feats; one wave per node
__global__ __launch_bounds__(64) void k_attn_vec2(const float* __restrict__ h2,
                                                  const float* __restrict__ a2s,
                                                  const float* __restrict__ a2d,
                                                  float* __restrict__ as2,
                                                  float* __restrict__ ad2) {
    int node = blockIdx.x;
    int lane = threadIdx.x;
    float4 hv = *(const float4*)(h2 + (size_t)node * D_OUT + lane * 4);
    float4 sv = *(const float4*)(a2s + lane * 4);
    float4 dv = *(const float4*)(a2d + lane * 4);
    float s_ = hv.x * sv.x + hv.y * sv.y + hv.z * sv.z + hv.w * sv.w;
    float d_ = hv.x * dv.x + hv.y * dv.y + hv.z * dv.z + hv.w * dv.w;
    #pragma unroll
    for (int off = 32; off >= 1; off >>= 1) {
        s_ += __shfl_xor(s_, off, 64);
        d_ += __shfl_xor(d_, off, 64);
    }
    if (lane == 0) { as2[node] = s_; ad2[node] = d_; }
}

// ---------------- edge aggregation ----------------

// layer 1: per dst-node block; 4 heads x 128 feats; writes ELU(out + b1)
__global__ __launch_bounds__(256) void k_edge1(const int* __restrict__ row_start,
                                               const int* __restrict__ csr_src,
                                               const float* __restrict__ h1,
                                               const float* __restrict__ as1,
                                               const float* __restrict__ ad1,
                                               const float* __restrict__ b1,
                                               float* __restrict__ helu) {
    int node = blockIdx.x;
    int tid = threadIdx.x;
    int wave = tid >> 6, lane = tid & 63;
    int start = row_start[node];
    int end   = row_start[node + 1];

    float4 adv = *(const float4*)(ad1 + node * 4);
    float ad[4] = {adv.x, adv.y, adv.z, adv.w};

    // pass 1: per-head max of leaky logits
    float mx[4] = {NEG_INF, NEG_INF, NEG_INF, NEG_INF};
    for (int i = start + tid; i < end; i += 256) {
        int src = csr_src[i];
        float4 asv = *(const float4*)(as1 + src * 4);
        float l;
        l = asv.x + ad[0]; l = l > 0.f ? l : SLOPE * l; mx[0] = fmaxf(mx[0], l);
        l = asv.y + ad[1]; l = l > 0.f ? l : SLOPE * l; mx[1] = fmaxf(mx[1], l);
        l = asv.z + ad[2]; l = l > 0.f ? l : SLOPE * l; mx[2] = fmaxf(mx[2], l);
        l = asv.w + ad[3]; l = l > 0.f ? l : SLOPE * l; mx[3] = fmaxf(mx[3], l);
    }
    #pragma unroll
    for (int off = 32; off >= 1; off >>= 1) {
        #pragma unroll
        for (int h = 0; h < 4; h++) mx[h] = fmaxf(mx[h], __shfl_xor(mx[h], off, 64));
    }
    __shared__ float smx[4][4];
    if (lane == 0) {
        #pragma unroll
        for (int h = 0; h < 4; h++) smx[wave][h] = mx[h];
    }
    __syncthreads();
    float mh[4];
    #pragma unroll
    for (int h = 0; h < 4; h++)
        mh[h] = fmaxf(fmaxf(smx[0][h], smx[1][h]), fmaxf(smx[2][h], smx[3][h]));

    // pass 2: wave-per-edge; accumulate ex-weighted rows + per-head ex sums
    int h_lane = lane >> 4;          // features lane*8.. are inside head lane/16
    float mhl = mh[h_lane];
    float adl = ad[h_lane];
    bool sum_lane = ((lane & 15) == 0);
    float acc[8] = {0.f,0.f,0.f,0.f,0.f,0.f,0.f,0.f};
    float sum_local = 0.f;
    for (int i = start + wave; i < end; i += 4) {
        int src = csr_src[i];
        float l = as1[src * 4 + h_lane] + adl;
        l = l > 0.f ? l : SLOPE * l;
        float ex = __expf(l - mhl);
        if (sum_lane) sum_local += ex;
        const float* hr = h1 + (size_t)src * F1 + lane * 8;
        float4 v0 = *(const float4*)hr;
        float4 v1 = *(const float4*)(hr + 4);
        acc[0] += v0.x * ex; acc[1] += v0.y * ex; acc[2] += v0.z * ex; acc[3] += v0.w * ex;
        acc[4] += v1.x * ex; acc[5] += v1.y * ex; acc[6] += v1.z * ex; acc[7] += v1.w * ex;
    }
    __shared__ float sacc[4][F1];
    __shared__ float ssum[4][4];
    *(float4*)&sacc[wave][lane * 8 + 0] = make_float4(acc[0], acc[1], acc[2], acc[3]);
    *(float4*)&sacc[wave][lane * 8 + 4] = make_float4(acc[4], acc[5], acc[6], acc[7]);
    if (sum_lane) ssum[wave][h_lane] = sum_local;
    __syncthreads();
    #pragma unroll
    for (int f = tid; f < F1; f += 256) {
        float v = sacc[0][f] + sacc[1][f] + sacc[2][f] + sacc[3][f];
        int h = f >> 7;
        float s = ssum[0][h] + ssum[1][h] + ssum[2][h] + ssum[3][h];
        v = v / s + b1[f];
        v = v > 0.f ? v : (__expf(v) - 1.f);   // ELU
        helu[(size_t)node * F1 + f] = v;
    }
}

// layer 2: single head, 256 feats; writes final output (+b2)
__global__ __launch_bounds__(256) void k_edge2(const int* __restrict__ row_start,
                                               const int* __restrict__ csr_src,
                                               const float* __restrict__ h2,
                                               const float* __restrict__ as2,
                                               const float* __restrict__ ad2,
                                               const float* __restrict__ b2,
                                               float* __restrict__ out) {
    int node = blockIdx.x;
    int tid = threadIdx.x;
    int wave = tid >> 6, lane = tid & 63;
    int start = row_start[node];
    int end   = row_start[node + 1];

    float ad = ad2[node];

    float mx = NEG_INF;
    for (int i = start + tid; i < end; i += 256) {
        int src = csr_src[i];
        float l = as2[src] + ad;
        l = l > 0.f ? l : SLOPE * l;
        mx = fmaxf(mx, l);
    }
    #pragma unroll
    for (int off = 32; off >= 1; off >>= 1) mx = fmaxf(mx, __shfl_xor(mx, off, 64));
    __shared__ float smx2[4];
    if (lane == 0) smx2[wave] = mx;
    __syncthreads();
    float m_ = fmaxf(fmaxf(smx2[0], smx2[1]), fmaxf(smx2[2], smx2[3]));

    float acc[4] = {0.f, 0.f, 0.f, 0.f};
    float sum_local = 0.f;
    for (int i = start + wave; i < end; i += 4) {
        int src = csr_src[i];
        float l = as2[src] + ad;
        l = l > 0.f ? l : SLOPE * l;
        float ex = __expf(l - m_);
        if (lane == 0) sum_local += ex;
        float4 v = *(const float4*)(h2 + (size_t)src * D_OUT + lane * 4);
        acc[0] += v.x * ex; acc[1] += v.y * ex; acc[2] += v.z * ex; acc[3] += v.w * ex;
    }
    __shared__ float sacc2[4][D_OUT];
    __shared__ float ssum2[4];
    *(float4*)&sacc2[wave][lane * 4] = make_float4(acc[0], acc[1], acc[2], acc[3]);
    if (lane == 0) ssum2[wave] = sum_local;
    __syncthreads();
    int f = tid;
    float v = sacc2[0][f] + sacc2[1][f] + sacc2[2][f] + sacc2[3][f];
    float s = ssum2[0] + ssum2[1] + ssum2[2] + ssum2[3];
    out[(size_t)node * D_OUT + f] = v / s + b2[f];
}

// ---------------- launch ----------------

extern "C" void kernel_launch(void* const* d_in, const int* in_sizes, int n_in,
                              void* d_out, int out_size, void* d_ws, size_t ws_size,
                              hipStream_t stream) {
    const float* x   = (const float*)d_in[0];
    const int*   ei  = (const int*)d_in[1];
    const float* W1  = (const float*)d_in[2];
    const float* a1s = (const float*)d_in[3];
    const float* a1d = (const float*)d_in[4];
    const float* b1  = (const float*)d_in[5];
    const float* W2  = (const float*)d_in[6];
    const float* a2s = (const float*)d_in[7];
    const float* a2d = (const float*)d_in[8];
    const float* b2  = (const float*)d_in[9];
    float* out = (float*)d_out;

    char* ws = (char*)d_ws;
    size_t off = 0;
    auto take = [&](size_t bytes) {
        char* p = ws + off;
        off += (bytes + 255) & ~(size_t)255;
        return p;
    };
    int*   deg       = (int*)take(sizeof(int) * N_NODES);
    int*   row_start = (int*)take(sizeof(int) * (N_NODES + 1));
    int*   cursor    = (int*)take(sizeof(int) * N_NODES);
    int*   csr_src   = (int*)take(sizeof(int) * E_TOT);
    float* h1        = (float*)take(sizeof(float) * (size_t)N_NODES * F1);
    float* as1       = (float*)take(sizeof(float) * N_NODES * 4);
    float* ad1       = (float*)take(sizeof(float) * N_NODES * 4);
    float* helu      = (float*)take(sizeof(float) * (size_t)N_NODES * F1);
    float* h2        = (float*)take(sizeof(float) * (size_t)N_NODES * D_OUT);
    float* as2       = (float*)take(sizeof(float) * N_NODES);
    float* ad2       = (float*)take(sizeof(float) * N_NODES);

    hipMemsetAsync(deg, 0, sizeof(int) * N_NODES, stream);

    int eblocks = (E_TOT + 255) / 256;
    k_hist<<<eblocks, 256, 0, stream>>>(ei, deg);
    k_scan<<<1, 256, 0, stream>>>(deg, row_start, cursor);
    k_scatter<<<eblocks, 256, 0, stream>>>(ei, cursor, csr_src);

    // layer 1
    k_gemm<<<dim3(F1 / 64, (N_NODES + 63) / 64), 256, 0, stream>>>(x, W1, h1, N_NODES, F1, D_IN);
    k_attn_vec1<<<N_NODES, 256, 0, stream>>>(h1, a1s, a1d, as1, ad1);
    k_edge1<<<N_NODES, 256, 0, stream>>>(row_start, csr_src, h1, as1, ad1, b1, helu);

    // layer 2
    k_gemm<<<dim3(D_OUT / 64, (N_NODES + 63) / 64), 256, 0, stream>>>(helu, W2, h2, N_NODES, D_OUT, F1);
    k_attn_vec2<<<N_NODES, 64, 0, stream>>>(h2, a2s, a2d, as2, ad2);
    k_edge2<<<N_NODES, 256, 0, stream>>>(row_start, csr_src, h2, as2, ad2, b2, out);
}

// Round 2
// 253.081 us; speedup vs baseline: 1.2807x; 1.2807x over previous
//
#include <hip/hip_runtime.h>

#define N_NODES 10000
#define E_RAW   320000
#define E_TOT   330000
#define D_IN    256
#define HID     128
#define HEADS   4
#define F1      512   // HEADS*HID
#define D_OUT   256
#define SLOPE   0.2f
#define NEG_INF -3.0e38f

typedef __attribute__((ext_vector_type(8))) short bf16x8;
typedef __attribute__((ext_vector_type(4))) float f32x4;

__device__ __forceinline__ float bf2f(ushort u) {
    return __uint_as_float(((uint)u) << 16);
}
__device__ __forceinline__ ushort f2bf(float x) {
    uint u = __float_as_uint(x);
    uint r = (u + 0x7FFFu + ((u >> 16) & 1u)) >> 16;
    return (ushort)r;
}

// ---------------- CSR build ----------------

__global__ __launch_bounds__(256) void k_hist(const int* __restrict__ ei, int* __restrict__ deg) {
    int e = blockIdx.x * 256 + threadIdx.x;
    if (e < E_TOT) {
        int dst = (e < E_RAW) ? ei[E_RAW + e] : (e - E_RAW);
        atomicAdd(&deg[dst], 1);
    }
}

__global__ __launch_bounds__(256) void k_scan(const int* __restrict__ deg,
                                              int* __restrict__ row_start,
                                              int* __restrict__ cursor) {
    __shared__ int buf[256];
    __shared__ int carry_s;
    int tid = threadIdx.x;
    if (tid == 0) carry_s = 0;
    __syncthreads();
    for (int base = 0; base < N_NODES; base += 256) {
        int idx = base + tid;
        int v = (idx < N_NODES) ? deg[idx] : 0;
        buf[tid] = v;
        __syncthreads();
        for (int off = 1; off < 256; off <<= 1) {
            int t = (tid >= off) ? buf[tid - off] : 0;
            __syncthreads();
            buf[tid] += t;
            __syncthreads();
        }
        int incl = buf[tid];
        int excl = incl - v;
        int carry = carry_s;
        if (idx < N_NODES) {
            row_start[idx] = carry + excl;
            cursor[idx]    = carry + excl;
        }
        __syncthreads();
        if (tid == 255) carry_s = carry + incl;
        __syncthreads();
    }
    if (tid == 0) row_start[N_NODES] = E_TOT;
}

__global__ __launch_bounds__(256) void k_scatter(const int* __restrict__ ei,
                                                 int* __restrict__ cursor,
                                                 int* __restrict__ csr_src) {
    int e = blockIdx.x * 256 + threadIdx.x;
    if (e < E_TOT) {
        int src = (e < E_RAW) ? ei[e] : (e - E_RAW);
        int dst = (e < E_RAW) ? ei[E_RAW + e] : (e - E_RAW);
        int pos = atomicAdd(&cursor[dst], 1);
        csr_src[pos] = src;
    }
}

// ---------------- hi/lo bf16 split helpers ----------------

// split flat f32 array -> hi/lo bf16 arrays
__global__ __launch_bounds__(256) void k_split(const float* __restrict__ in,
                                               ushort* __restrict__ hi,
                                               ushort* __restrict__ lo, int n) {
    int i = blockIdx.x * 256 + threadIdx.x;
    if (i < n) {
        float x = in[i];
        ushort h = f2bf(x);
        hi[i] = h;
        lo[i] = f2bf(x - bf2f(h));
    }
}

// split + transpose: in [K][N] f32 -> out [N][K] hi/lo bf16
__global__ __launch_bounds__(256) void k_splitT(const float* __restrict__ in,
                                                ushort* __restrict__ hi,
                                                ushort* __restrict__ lo,
                                                int K, int N) {
    int i = blockIdx.x * 256 + threadIdx.x;
    if (i < K * N) {
        int k = i / N, n = i - k * N;
        float x = in[i];
        ushort h = f2bf(x);
        size_t o = (size_t)n * K + k;
        hi[o] = h;
        lo[o] = f2bf(x - bf2f(h));
    }
}

// ---------------- MFMA split-bf16 GEMM ----------------
// C[M,N] = A[M,K] @ B[K,N], A given as hi/lo bf16 [M][K], B as hi/lo bf16 [N][K] (pre-transposed).
// 3-product split: Ah*Bh + Ah*Bl + Al*Bh  (~f32 accuracy).
// BM=128 BN=64 BK=64, 256 threads = 4 waves (2x2), 16x16x32 MFMA, per-wave 64x32 out.

template<bool OUT_BF16>
__global__ __launch_bounds__(256) void k_gemm_mfma(const ushort* __restrict__ Ah,
                                                   const ushort* __restrict__ Al,
                                                   const ushort* __restrict__ Bh,
                                                   const ushort* __restrict__ Bl,
                                                   void* __restrict__ Cv,
                                                   int M, int N, int K) {
    __shared__ ushort sAh[128][72];
    __shared__ ushort sAl[128][72];
    __shared__ ushort sBh[64][72];
    __shared__ ushort sBl[64][72];

    const int tid = threadIdx.x;
    const int lane = tid & 63;
    const int wid = tid >> 6;
    const int wr = wid >> 1;      // 0..1
    const int wc = wid & 1;       // 0..1
    const int m0 = blockIdx.y * 128;
    const int n0 = blockIdx.x * 64;
    const int fr = lane & 15;
    const int fk = (lane >> 4) * 8;

    f32x4 acc[4][2];
    #pragma unroll
    for (int i = 0; i < 4; i++)
        #pragma unroll
        for (int j = 0; j < 2; j++) acc[i][j] = (f32x4){0.f, 0.f, 0.f, 0.f};

    for (int k0 = 0; k0 < K; k0 += 64) {
        // stage A tiles (128x64 hi + lo): 1024 16B-chunks each, 4 per thread
        #pragma unroll
        for (int i = 0; i < 4; i++) {
            int c = tid + 256 * i;
            int row = c >> 3, kc = (c & 7) << 3;
            int gr = m0 + row;
            gr = gr < M ? gr : M - 1;
            size_t go = (size_t)gr * K + k0 + kc;
            *(float4*)&sAh[row][kc] = *(const float4*)&Ah[go];
            *(float4*)&sAl[row][kc] = *(const float4*)&Al[go];
        }
        // stage B tiles (64x64 hi + lo): 512 chunks each, 2 per thread
        #pragma unroll
        for (int i = 0; i < 2; i++) {
            int c = tid + 256 * i;
            int col = c >> 3, kc = (c & 7) << 3;
            size_t go = (size_t)(n0 + col) * K + k0 + kc;
            *(float4*)&sBh[col][kc] = *(const float4*)&Bh[go];
            *(float4*)&sBl[col][kc] = *(const float4*)&Bl[go];
        }
        __syncthreads();
        #pragma unroll
        for (int kk = 0; kk < 2; kk++) {
            int kb = kk * 32 + fk;
            bf16x8 a_h[4], a_l[4], b_h[2], b_l[2];
            #pragma unroll
            for (int i = 0; i < 4; i++) {
                int r = wr * 64 + i * 16 + fr;
                a_h[i] = *(const bf16x8*)&sAh[r][kb];
                a_l[i] = *(const bf16x8*)&sAl[r][kb];
            }
            #pragma unroll
            for (int j = 0; j < 2; j++) {
                int cc = wc * 32 + j * 16 + fr;
                b_h[j] = *(const bf16x8*)&sBh[cc][kb];
                b_l[j] = *(const bf16x8*)&sBl[cc][kb];
            }
            #pragma unroll
            for (int i = 0; i < 4; i++)
                #pragma unroll
                for (int j = 0; j < 2; j++) {
                    acc[i][j] = __builtin_amdgcn_mfma_f32_16x16x32_bf16(a_h[i], b_h[j], acc[i][j], 0, 0, 0);
                    acc[i][j] = __builtin_amdgcn_mfma_f32_16x16x32_bf16(a_h[i], b_l[j], acc[i][j], 0, 0, 0);
                    acc[i][j] = __builtin_amdgcn_mfma_f32_16x16x32_bf16(a_l[i], b_h[j], acc[i][j], 0, 0, 0);
                }
        }
        __syncthreads();
    }

    // epilogue: C/D layout col=lane&15, row=(lane>>4)*4+q
    #pragma unroll
    for (int i = 0; i < 4; i++) {
        #pragma unroll
        for (int j = 0; j < 2; j++) {
            int row_base = m0 + wr * 64 + i * 16 + ((lane >> 4) << 2);
            int col = n0 + wc * 32 + j * 16 + (lane & 15);
            #pragma unroll
            for (int q = 0; q < 4; q++) {
                int r = row_base + q;
                if (r < M) {
                    if (OUT_BF16) ((ushort*)Cv)[(size_t)r * N + col] = f2bf(acc[i][j][q]);
                    else          ((float*)Cv)[(size_t)r * N + col] = acc[i][j][q];
                }
            }
        }
    }
}

// ---------------- attention vectors ----------------

// layer 1 (h1 in bf16): per node/head dot with a1_src, a1_dst
__global__ __launch_bounds__(256) void k_attn_vec1(const ushort* __restrict__ h1,
                                                   const float* __restrict__ a1s,
                                                   const float* __restrict__ a1d,
                                                   float* __restrict__ as1,
                                                   float* __restrict__ ad1) {
    int node = blockIdx.x;
    int tid = threadIdx.x;
    int wave = tid >> 6;   // = head
    int lane = tid & 63;
    const ushort* hr = h1 + (size_t)node * F1 + wave * HID;
    const float* svp = a1s + wave * HID;
    const float* dvp = a1d + wave * HID;
    float h0 = bf2f(hr[lane]), h1v = bf2f(hr[lane + 64]);
    float s_ = h0 * svp[lane] + h1v * svp[lane + 64];
    float d_ = h0 * dvp[lane] + h1v * dvp[lane + 64];
    #pragma unroll
    for (int off = 32; off >= 1; off >>= 1) {
        s_ += __shfl_xor(s_, off, 64);
        d_ += __shfl_xor(d_, off, 64);
    }
    if (lane == 0) {
        as1[node * 4 + wave] = s_;
        ad1[node * 4 + wave] = d_;
    }
}

// layer 2: single head over 256 feats (h2 f32); one wave per node
__global__ __launch_bounds__(64) void k_attn_vec2(const float* __restrict__ h2,
                                                  const float* __restrict__ a2s,
                                                  const float* __restrict__ a2d,
                                                  float* __restrict__ as2,
                                                  float* __restrict__ ad2) {
    int node = blockIdx.x;
    int lane = threadIdx.x;
    float4 hv = *(const float4*)(h2 + (size_t)node * D_OUT + lane * 4);
    float4 sv = *(const float4*)(a2s + lane * 4);
    float4 dv = *(const float4*)(a2d + lane * 4);
    float s_ = hv.x * sv.x + hv.y * sv.y + hv.z * sv.z + hv.w * sv.w;
    float d_ = hv.x * dv.x + hv.y * dv.y + hv.z * dv.z + hv.w * dv.w;
    #pragma unroll
    for (int off = 32; off >= 1; off >>= 1) {
        s_ += __shfl_xor(s_, off, 64);
        d_ += __shfl_xor(d_, off, 64);
    }
    if (lane == 0) { as2[node] = s_; ad2[node] = d_; }
}

// ---------------- edge aggregation ----------------

union V16 { float4 f; ushort u[8]; };

// layer 1: per dst-node block; gathers bf16 h1 rows; writes ELU(out+b1) as hi/lo bf16
__global__ __launch_bounds__(256) void k_edge1(const int* __restrict__ row_start,
                                               const int* __restrict__ csr_src,
                                               const ushort* __restrict__ h1,
                                               const float* __restrict__ as1,
                                               const float* __restrict__ ad1,
                                               const float* __restrict__ b1,
                                               ushort* __restrict__ heluh,
                                               ushort* __restrict__ helul) {
    int node = blockIdx.x;
    int tid = threadIdx.x;
    int wave = tid >> 6, lane = tid & 63;
    int start = row_start[node];
    int end   = row_start[node + 1];

    float4 adv = *(const float4*)(ad1 + node * 4);
    float ad[4] = {adv.x, adv.y, adv.z, adv.w};

    // pass 1: per-head max of leaky logits
    float mx[4] = {NEG_INF, NEG_INF, NEG_INF, NEG_INF};
    for (int i = start + tid; i < end; i += 256) {
        int src = csr_src[i];
        float4 asv = *(const float4*)(as1 + src * 4);
        float l;
        l = asv.x + ad[0]; l = l > 0.f ? l : SLOPE * l; mx[0] = fmaxf(mx[0], l);
        l = asv.y + ad[1]; l = l > 0.f ? l : SLOPE * l; mx[1] = fmaxf(mx[1], l);
        l = asv.z + ad[2]; l = l > 0.f ? l : SLOPE * l; mx[2] = fmaxf(mx[2], l);
        l = asv.w + ad[3]; l = l > 0.f ? l : SLOPE * l; mx[3] = fmaxf(mx[3], l);
    }
    #pragma unroll
    for (int off = 32; off >= 1; off >>= 1) {
        #pragma unroll
        for (int h = 0; h < 4; h++) mx[h] = fmaxf(mx[h], __shfl_xor(mx[h], off, 64));
    }
    __shared__ float smx[4][4];
    if (lane == 0) {
        #pragma unroll
        for (int h = 0; h < 4; h++) smx[wave][h] = mx[h];
    }
    __syncthreads();
    float mh[4];
    #pragma unroll
    for (int h = 0; h < 4; h++)
        mh[h] = fmaxf(fmaxf(smx[0][h], smx[1][h]), fmaxf(smx[2][h], smx[3][h]));

    // pass 2: wave-per-edge; bf16 row gather (64 lanes x 8 bf16 = full 512 row)
    int h_lane = lane >> 4;
    float mhl = mh[h_lane];
    float adl = ad[h_lane];
    bool sum_lane = ((lane & 15) == 0);
    float acc[8] = {0.f,0.f,0.f,0.f,0.f,0.f,0.f,0.f};
    float sum_local = 0.f;
    for (int i = start + wave; i < end; i += 4) {
        int src = csr_src[i];
        float l = as1[src * 4 + h_lane] + adl;
        l = l > 0.f ? l : SLOPE * l;
        float ex = __expf(l - mhl);
        if (sum_lane) sum_local += ex;
        V16 v;
        v.f = *(const float4*)(h1 + (size_t)src * F1 + lane * 8);
        #pragma unroll
        for (int k = 0; k < 8; k++) acc[k] += bf2f(v.u[k]) * ex;
    }
    __shared__ float sacc[4][F1];
    __shared__ float ssum[4][4];
    *(float4*)&sacc[wave][lane * 8 + 0] = make_float4(acc[0], acc[1], acc[2], acc[3]);
    *(float4*)&sacc[wave][lane * 8 + 4] = make_float4(acc[4], acc[5], acc[6], acc[7]);
    if (sum_lane) ssum[wave][h_lane] = sum_local;
    __syncthreads();
    #pragma unroll
    for (int f = tid; f < F1; f += 256) {
        float v = sacc[0][f] + sacc[1][f] + sacc[2][f] + sacc[3][f];
        int h = f >> 7;
        float s = ssum[0][h] + ssum[1][h] + ssum[2][h] + ssum[3][h];
        v = v / s + b1[f];
        v = v > 0.f ? v : (__expf(v) - 1.f);   // ELU
        size_t o = (size_t)node * F1 + f;
        ushort hv = f2bf(v);
        heluh[o] = hv;
        helul[o] = f2bf(v - bf2f(hv));
    }
}

// layer 2: single head, 256 feats, h2 f32; writes final output (+b2)
__global__ __launch_bounds__(256) void k_edge2(const int* __restrict__ row_start,
                                               const int* __restrict__ csr_src,
                                               const float* __restrict__ h2,
                                               const float* __restrict__ as2,
                                               const float* __restrict__ ad2,
                                               const float* __restrict__ b2,
                                               float* __restrict__ out) {
    int node = blockIdx.x;
    int tid = threadIdx.x;
    int wave = tid >> 6, lane = tid & 63;
    int start = row_start[node];
    int end   = row_start[node + 1];

    float ad = ad2[node];

    float mx = NEG_INF;
    for (int i = start + tid; i < end; i += 256) {
        int src = csr_src[i];
        float l = as2[src] + ad;
        l = l > 0.f ? l : SLOPE * l;
        mx = fmaxf(mx, l);
    }
    #pragma unroll
    for (int off = 32; off >= 1; off >>= 1) mx = fmaxf(mx, __shfl_xor(mx, off, 64));
    __shared__ float smx2[4];
    if (lane == 0) smx2[wave] = mx;
    __syncthreads();
    float m_ = fmaxf(fmaxf(smx2[0], smx2[1]), fmaxf(smx2[2], smx2[3]));

    float acc[4] = {0.f, 0.f, 0.f, 0.f};
    float sum_local = 0.f;
    for (int i = start + wave; i < end; i += 4) {
        int src = csr_src[i];
        float l = as2[src] + ad;
        l = l > 0.f ? l : SLOPE * l;
        float ex = __expf(l - m_);
        if (lane == 0) sum_local += ex;
        float4 v = *(const float4*)(h2 + (size_t)src * D_OUT + lane * 4);
        acc[0] += v.x * ex; acc[1] += v.y * ex; acc[2] += v.z * ex; acc[3] += v.w * ex;
    }
    __shared__ float sacc2[4][D_OUT];
    __shared__ float ssum2[4];
    *(float4*)&sacc2[wave][lane * 4] = make_float4(acc[0], acc[1], acc[2], acc[3]);
    if (lane == 0) ssum2[wave] = sum_local;
    __syncthreads();
    int f = tid;
    float v = sacc2[0][f] + sacc2[1][f] + sacc2[2][f] + sacc2[3][f];
    float s = ssum2[0] + ssum2[1] + ssum2[2] + ssum2[3];
    out[(size_t)node * D_OUT + f] = v / s + b2[f];
}

// ---------------- launch ----------------

extern "C" void kernel_launch(void* const* d_in, const int* in_sizes, int n_in,
                              void* d_out, int out_size, void* d_ws, size_t ws_size,
                              hipStream_t stream) {
    const float* x   = (const float*)d_in[0];
    const int*   ei  = (const int*)d_in[1];
    const float* W1  = (const float*)d_in[2];
    const float* a1s = (const float*)d_in[3];
    const float* a1d = (const float*)d_in[4];
    const float* b1  = (const float*)d_in[5];
    const float* W2  = (const float*)d_in[6];
    const float* a2s = (const float*)d_in[7];
    const float* a2d = (const float*)d_in[8];
    const float* b2  = (const float*)d_in[9];
    float* out = (float*)d_out;

    char* ws = (char*)d_ws;
    size_t off = 0;
    auto take = [&](size_t bytes) {
        char* p = ws + off;
        off += (bytes + 255) & ~(size_t)255;
        return p;
    };
    int*    deg       = (int*)take(sizeof(int) * N_NODES);
    int*    row_start = (int*)take(sizeof(int) * (N_NODES + 1));
    int*    cursor    = (int*)take(sizeof(int) * N_NODES);
    int*    csr_src   = (int*)take(sizeof(int) * E_TOT);
    ushort* xhi       = (ushort*)take(sizeof(ushort) * (size_t)N_NODES * D_IN);
    ushort* xlo       = (ushort*)take(sizeof(ushort) * (size_t)N_NODES * D_IN);
    ushort* w1h       = (ushort*)take(sizeof(ushort) * D_IN * F1);
    ushort* w1l       = (ushort*)take(sizeof(ushort) * D_IN * F1);
    ushort* w2h       = (ushort*)take(sizeof(ushort) * F1 * D_OUT);
    ushort* w2l       = (ushort*)take(sizeof(ushort) * F1 * D_OUT);
    ushort* h1        = (ushort*)take(sizeof(ushort) * (size_t)N_NODES * F1);
    float*  as1       = (float*)take(sizeof(float) * N_NODES * 4);
    float*  ad1       = (float*)take(sizeof(float) * N_NODES * 4);
    ushort* heluh     = (ushort*)take(sizeof(ushort) * (size_t)N_NODES * F1);
    ushort* helul     = (ushort*)take(sizeof(ushort) * (size_t)N_NODES * F1);
    float*  h2        = (float*)take(sizeof(float) * (size_t)N_NODES * D_OUT);
    float*  as2       = (float*)take(sizeof(float) * N_NODES);
    float*  ad2       = (float*)take(sizeof(float) * N_NODES);

    hipMemsetAsync(deg, 0, sizeof(int) * N_NODES, stream);

    int eblocks = (E_TOT + 255) / 256;
    k_hist<<<eblocks, 256, 0, stream>>>(ei, deg);
    k_scan<<<1, 256, 0, stream>>>(deg, row_start, cursor);
    k_scatter<<<eblocks, 256, 0, stream>>>(ei, cursor, csr_src);

    // splits
    int nx = N_NODES * D_IN;
    k_split<<<(nx + 255) / 256, 256, 0, stream>>>(x, xhi, xlo, nx);
    k_splitT<<<(D_IN * F1 + 255) / 256, 256, 0, stream>>>(W1, w1h, w1l, D_IN, F1);
    k_splitT<<<(F1 * D_OUT + 255) / 256, 256, 0, stream>>>(W2, w2h, w2l, F1, D_OUT);

    // layer 1
    k_gemm_mfma<true><<<dim3(F1 / 64, (N_NODES + 127) / 128), 256, 0, stream>>>(
        xhi, xlo, w1h, w1l, (void*)h1, N_NODES, F1, D_IN);
    k_attn_vec1<<<N_NODES, 256, 0, stream>>>(h1, a1s, a1d, as1, ad1);
    k_edge1<<<N_NODES, 256, 0, stream>>>(row_start, csr_src, h1, as1, ad1, b1, heluh, helul);

    // layer 2
    k_gemm_mfma<false><<<dim3(D_OUT / 64, (N_NODES + 127) / 128), 256, 0, stream>>>(
        heluh, helul, w2h, w2l, (void*)h2, N_NODES, D_OUT, F1);
    k_attn_vec2<<<N_NODES, 64, 0, stream>>>(h2, a2s, a2d, as2, ad2);
    k_edge2<<<N_NODES, 256, 0, stream>>>(row_start, csr_src, h2, as2, ad2, b2, out);
}

// Round 3
// 229.338 us; speedup vs baseline: 1.4133x; 1.1035x over previous
//
#include <hip/hip_runtime.h>

#define N_NODES 10000
#define E_RAW   320000
#define E_TOT   330000
#define D_IN    256
#define HID     128
#define HEADS   4
#define F1      512   // HEADS*HID
#define D_OUT   256
#define SLOPE   0.2f
#define NEG_INF -3.0e38f

typedef __attribute__((ext_vector_type(8))) short bf16x8;
typedef __attribute__((ext_vector_type(4))) float f32x4;

__device__ __forceinline__ float bf2f(ushort u) {
    return __uint_as_float(((uint)u) << 16);
}
__device__ __forceinline__ ushort f2bf(float x) {
    uint u = __float_as_uint(x);
    uint r = (u + 0x7FFFu + ((u >> 16) & 1u)) >> 16;
    return (ushort)r;
}
// unpack a u32 holding 2 bf16 (low = even feat, high = odd feat)
__device__ __forceinline__ float bfu_lo(uint u) { return __uint_as_float(u << 16); }
__device__ __forceinline__ float bfu_hi(uint u) { return __uint_as_float(u & 0xFFFF0000u); }

// ---------------- CSR build ----------------

__global__ __launch_bounds__(256) void k_hist(const int* __restrict__ ei, int* __restrict__ deg) {
    int e = blockIdx.x * 256 + threadIdx.x;
    if (e < E_TOT) {
        int dst = (e < E_RAW) ? ei[E_RAW + e] : (e - E_RAW);
        atomicAdd(&deg[dst], 1);
    }
}

__global__ __launch_bounds__(256) void k_scan(const int* __restrict__ deg,
                                              int* __restrict__ row_start,
                                              int* __restrict__ cursor) {
    __shared__ int buf[256];
    __shared__ int carry_s;
    int tid = threadIdx.x;
    if (tid == 0) carry_s = 0;
    __syncthreads();
    for (int base = 0; base < N_NODES; base += 256) {
        int idx = base + tid;
        int v = (idx < N_NODES) ? deg[idx] : 0;
        buf[tid] = v;
        __syncthreads();
        for (int off = 1; off < 256; off <<= 1) {
            int t = (tid >= off) ? buf[tid - off] : 0;
            __syncthreads();
            buf[tid] += t;
            __syncthreads();
        }
        int incl = buf[tid];
        int excl = incl - v;
        int carry = carry_s;
        if (idx < N_NODES) {
            row_start[idx] = carry + excl;
            cursor[idx]    = carry + excl;
        }
        __syncthreads();
        if (tid == 255) carry_s = carry + incl;
        __syncthreads();
    }
    if (tid == 0) row_start[N_NODES] = E_TOT;
}

__global__ __launch_bounds__(256) void k_scatter(const int* __restrict__ ei,
                                                 int* __restrict__ cursor,
                                                 int* __restrict__ csr_src) {
    int e = blockIdx.x * 256 + threadIdx.x;
    if (e < E_TOT) {
        int src = (e < E_RAW) ? ei[e] : (e - E_RAW);
        int dst = (e < E_RAW) ? ei[E_RAW + e] : (e - E_RAW);
        int pos = atomicAdd(&cursor[dst], 1);
        csr_src[pos] = src;
    }
}

// ---------------- hi/lo bf16 split helpers ----------------

__global__ __launch_bounds__(256) void k_split(const float* __restrict__ in,
                                               ushort* __restrict__ hi,
                                               ushort* __restrict__ lo, int n) {
    int i = blockIdx.x * 256 + threadIdx.x;
    if (i < n) {
        float x = in[i];
        ushort h = f2bf(x);
        hi[i] = h;
        lo[i] = f2bf(x - bf2f(h));
    }
}

__global__ __launch_bounds__(256) void k_splitT(const float* __restrict__ in,
                                                ushort* __restrict__ hi,
                                                ushort* __restrict__ lo,
                                                int K, int N) {
    int i = blockIdx.x * 256 + threadIdx.x;
    if (i < K * N) {
        int k = i / N, n = i - k * N;
        float x = in[i];
        ushort h = f2bf(x);
        size_t o = (size_t)n * K + k;
        hi[o] = h;
        lo[o] = f2bf(x - bf2f(h));
    }
}

// ---------------- MFMA split-bf16 GEMM ----------------
// C[M,N] = A[M,K] @ B[K,N]; A hi/lo bf16 [M][K], B hi/lo bf16 [N][K] (pre-transposed).
// 3-product split: Ah*Bh + Ah*Bl + Al*Bh. BM=128 BN=64 BK=64, 4 waves (2x2).

template<bool OUT_BF16>
__global__ __launch_bounds__(256) void k_gemm_mfma(const ushort* __restrict__ Ah,
                                                   const ushort* __restrict__ Al,
                                                   const ushort* __restrict__ Bh,
                                                   const ushort* __restrict__ Bl,
                                                   void* __restrict__ Cv,
                                                   int M, int N, int K) {
    __shared__ ushort sAh[128][72];
    __shared__ ushort sAl[128][72];
    __shared__ ushort sBh[64][72];
    __shared__ ushort sBl[64][72];

    const int tid = threadIdx.x;
    const int lane = tid & 63;
    const int wid = tid >> 6;
    const int wr = wid >> 1;
    const int wc = wid & 1;
    const int m0 = blockIdx.y * 128;
    const int n0 = blockIdx.x * 64;
    const int fr = lane & 15;
    const int fk = (lane >> 4) * 8;

    f32x4 acc[4][2];
    #pragma unroll
    for (int i = 0; i < 4; i++)
        #pragma unroll
        for (int j = 0; j < 2; j++) acc[i][j] = (f32x4){0.f, 0.f, 0.f, 0.f};

    for (int k0 = 0; k0 < K; k0 += 64) {
        #pragma unroll
        for (int i = 0; i < 4; i++) {
            int c = tid + 256 * i;
            int row = c >> 3, kc = (c & 7) << 3;
            int gr = m0 + row;
            gr = gr < M ? gr : M - 1;
            size_t go = (size_t)gr * K + k0 + kc;
            *(float4*)&sAh[row][kc] = *(const float4*)&Ah[go];
            *(float4*)&sAl[row][kc] = *(const float4*)&Al[go];
        }
        #pragma unroll
        for (int i = 0; i < 2; i++) {
            int c = tid + 256 * i;
            int col = c >> 3, kc = (c & 7) << 3;
            size_t go = (size_t)(n0 + col) * K + k0 + kc;
            *(float4*)&sBh[col][kc] = *(const float4*)&Bh[go];
            *(float4*)&sBl[col][kc] = *(const float4*)&Bl[go];
        }
        __syncthreads();
        #pragma unroll
        for (int kk = 0; kk < 2; kk++) {
            int kb = kk * 32 + fk;
            bf16x8 a_h[4], a_l[4], b_h[2], b_l[2];
            #pragma unroll
            for (int i = 0; i < 4; i++) {
                int r = wr * 64 + i * 16 + fr;
                a_h[i] = *(const bf16x8*)&sAh[r][kb];
                a_l[i] = *(const bf16x8*)&sAl[r][kb];
            }
            #pragma unroll
            for (int j = 0; j < 2; j++) {
                int cc = wc * 32 + j * 16 + fr;
                b_h[j] = *(const bf16x8*)&sBh[cc][kb];
                b_l[j] = *(const bf16x8*)&sBl[cc][kb];
            }
            #pragma unroll
            for (int i = 0; i < 4; i++)
                #pragma unroll
                for (int j = 0; j < 2; j++) {
                    acc[i][j] = __builtin_amdgcn_mfma_f32_16x16x32_bf16(a_h[i], b_h[j], acc[i][j], 0, 0, 0);
                    acc[i][j] = __builtin_amdgcn_mfma_f32_16x16x32_bf16(a_h[i], b_l[j], acc[i][j], 0, 0, 0);
                    acc[i][j] = __builtin_amdgcn_mfma_f32_16x16x32_bf16(a_l[i], b_h[j], acc[i][j], 0, 0, 0);
                }
        }
        __syncthreads();
    }

    #pragma unroll
    for (int i = 0; i < 4; i++) {
        #pragma unroll
        for (int j = 0; j < 2; j++) {
            int row_base = m0 + wr * 64 + i * 16 + ((lane >> 4) << 2);
            int col = n0 + wc * 32 + j * 16 + (lane & 15);
            #pragma unroll
            for (int q = 0; q < 4; q++) {
                int r = row_base + q;
                if (r < M) {
                    if (OUT_BF16) ((ushort*)Cv)[(size_t)r * N + col] = f2bf(acc[i][j][q]);
                    else          ((float*)Cv)[(size_t)r * N + col] = acc[i][j][q];
                }
            }
        }
    }
}

// ---------------- attention vectors ----------------

__global__ __launch_bounds__(256) void k_attn_vec1(const ushort* __restrict__ h1,
                                                   const float* __restrict__ a1s,
                                                   const float* __restrict__ a1d,
                                                   float* __restrict__ as1,
                                                   float* __restrict__ ad1) {
    int node = blockIdx.x;
    int tid = threadIdx.x;
    int wave = tid >> 6;   // head
    int lane = tid & 63;
    const ushort* hr = h1 + (size_t)node * F1 + wave * HID;
    const float* svp = a1s + wave * HID;
    const float* dvp = a1d + wave * HID;
    float h0 = bf2f(hr[lane]), h1v = bf2f(hr[lane + 64]);
    float s_ = h0 * svp[lane] + h1v * svp[lane + 64];
    float d_ = h0 * dvp[lane] + h1v * dvp[lane + 64];
    #pragma unroll
    for (int off = 32; off >= 1; off >>= 1) {
        s_ += __shfl_xor(s_, off, 64);
        d_ += __shfl_xor(d_, off, 64);
    }
    if (lane == 0) {
        as1[node * 4 + wave] = s_;
        ad1[node * 4 + wave] = d_;
    }
}

// layer 2: bf16 h2; 4 nodes per 256-block, one wave per node
__global__ __launch_bounds__(256) void k_attn_vec2(const ushort* __restrict__ h2,
                                                   const float* __restrict__ a2s,
                                                   const float* __restrict__ a2d,
                                                   float* __restrict__ as2,
                                                   float* __restrict__ ad2) {
    int node = blockIdx.x * 4 + (threadIdx.x >> 6);
    int lane = threadIdx.x & 63;
    uint2 hv = *(const uint2*)(h2 + (size_t)node * D_OUT + lane * 4);
    float h0 = bfu_lo(hv.x), h1v = bfu_hi(hv.x), h2v = bfu_lo(hv.y), h3 = bfu_hi(hv.y);
    float4 sv = *(const float4*)(a2s + lane * 4);
    float4 dv = *(const float4*)(a2d + lane * 4);
    float s_ = h0 * sv.x + h1v * sv.y + h2v * sv.z + h3 * sv.w;
    float d_ = h0 * dv.x + h1v * dv.y + h2v * dv.z + h3 * dv.w;
    #pragma unroll
    for (int off = 32; off >= 1; off >>= 1) {
        s_ += __shfl_xor(s_, off, 64);
        d_ += __shfl_xor(d_, off, 64);
    }
    if (lane == 0) { as2[node] = s_; ad2[node] = d_; }
}

// ---------------- edge aggregation (one wave per node) ----------------

__device__ __forceinline__ void fma8(uint4 v, float e, float* acc) {
    acc[0] += bfu_lo(v.x) * e; acc[1] += bfu_hi(v.x) * e;
    acc[2] += bfu_lo(v.y) * e; acc[3] += bfu_hi(v.y) * e;
    acc[4] += bfu_lo(v.z) * e; acc[5] += bfu_hi(v.z) * e;
    acc[6] += bfu_lo(v.w) * e; acc[7] += bfu_hi(v.w) * e;
}

// layer 1: 4 heads x 128 feats; lane covers feats lane*8..lane*8+7 (head = lane>>4)
__global__ __launch_bounds__(256) void k_edge1(const int* __restrict__ row_start,
                                               const int* __restrict__ csr_src,
                                               const ushort* __restrict__ h1,
                                               const float* __restrict__ as1,
                                               const float* __restrict__ ad1,
                                               const float* __restrict__ b1,
                                               ushort* __restrict__ heluh,
                                               ushort* __restrict__ helul) {
    int node = blockIdx.x * 4 + (threadIdx.x >> 6);
    int lane = threadIdx.x & 63;
    int start = row_start[node];
    int end   = row_start[node + 1];
    int h_lane = lane >> 4;

    float4 adv = *(const float4*)(ad1 + node * 4);
    float ad_all[4] = {adv.x, adv.y, adv.z, adv.w};
    float adl = ad_all[h_lane];

    // pass 1: per-head max, edge-parallel across lanes
    float mx[4] = {NEG_INF, NEG_INF, NEG_INF, NEG_INF};
    for (int i = start + lane; i < end; i += 64) {
        int src = csr_src[i];
        float4 asv = *(const float4*)(as1 + src * 4);
        float l;
        l = asv.x + ad_all[0]; l = l > 0.f ? l : SLOPE * l; mx[0] = fmaxf(mx[0], l);
        l = asv.y + ad_all[1]; l = l > 0.f ? l : SLOPE * l; mx[1] = fmaxf(mx[1], l);
        l = asv.z + ad_all[2]; l = l > 0.f ? l : SLOPE * l; mx[2] = fmaxf(mx[2], l);
        l = asv.w + ad_all[3]; l = l > 0.f ? l : SLOPE * l; mx[3] = fmaxf(mx[3], l);
    }
    #pragma unroll
    for (int off = 32; off >= 1; off >>= 1) {
        #pragma unroll
        for (int h = 0; h < 4; h++) mx[h] = fmaxf(mx[h], __shfl_xor(mx[h], off, 64));
    }
    float mhl = mx[h_lane];

    // pass 2: whole wave per edge; ex identical within each 16-lane head group
    float accA[8] = {0,0,0,0,0,0,0,0}, accB[8] = {0,0,0,0,0,0,0,0};
    float sumA = 0.f, sumB = 0.f;
    const size_t lo8 = lane * 8;
    int i = start;
    for (; i + 1 < end; i += 2) {
        int s0 = csr_src[i], s1 = csr_src[i + 1];
        float l0 = as1[s0 * 4 + h_lane] + adl;
        float l1 = as1[s1 * 4 + h_lane] + adl;
        uint4 v0 = *(const uint4*)(h1 + (size_t)s0 * F1 + lo8);
        uint4 v1 = *(const uint4*)(h1 + (size_t)s1 * F1 + lo8);
        l0 = l0 > 0.f ? l0 : SLOPE * l0;
        l1 = l1 > 0.f ? l1 : SLOPE * l1;
        float e0 = __expf(l0 - mhl), e1 = __expf(l1 - mhl);
        sumA += e0; sumB += e1;
        fma8(v0, e0, accA);
        fma8(v1, e1, accB);
    }
    if (i < end) {
        int s0 = csr_src[i];
        float l0 = as1[s0 * 4 + h_lane] + adl;
        uint4 v0 = *(const uint4*)(h1 + (size_t)s0 * F1 + lo8);
        l0 = l0 > 0.f ? l0 : SLOPE * l0;
        float e0 = __expf(l0 - mhl);
        sumA += e0;
        fma8(v0, e0, accA);
    }
    float s = sumA + sumB;
    float inv = 1.f / s;

    // epilogue: feats lane*8..+7, ELU, hi/lo split, 16B store each
    size_t o = (size_t)node * F1 + lo8;
    const float* bp = b1 + lo8;
    uint hi_pack[4], lo_pack[4];
    #pragma unroll
    for (int j = 0; j < 4; j++) {
        float v0 = (accA[2*j]   + accB[2*j])   * inv + bp[2*j];
        float v1 = (accA[2*j+1] + accB[2*j+1]) * inv + bp[2*j+1];
        v0 = v0 > 0.f ? v0 : (__expf(v0) - 1.f);
        v1 = v1 > 0.f ? v1 : (__expf(v1) - 1.f);
        ushort h0 = f2bf(v0), h1p = f2bf(v1);
        hi_pack[j] = (uint)h0 | ((uint)h1p << 16);
        ushort l0 = f2bf(v0 - bf2f(h0)), l1 = f2bf(v1 - bf2f(h1p));
        lo_pack[j] = (uint)l0 | ((uint)l1 << 16);
    }
    *(uint4*)&heluh[o] = make_uint4(hi_pack[0], hi_pack[1], hi_pack[2], hi_pack[3]);
    *(uint4*)&helul[o] = make_uint4(lo_pack[0], lo_pack[1], lo_pack[2], lo_pack[3]);
}

// layer 2: single head, 256 feats bf16; lane covers feats lane*4..+3
__global__ __launch_bounds__(256) void k_edge2(const int* __restrict__ row_start,
                                               const int* __restrict__ csr_src,
                                               const ushort* __restrict__ h2,
                                               const float* __restrict__ as2,
                                               const float* __restrict__ ad2,
                                               const float* __restrict__ b2,
                                               float* __restrict__ out) {
    int node = blockIdx.x * 4 + (threadIdx.x >> 6);
    int lane = threadIdx.x & 63;
    int start = row_start[node];
    int end   = row_start[node + 1];

    float ad = ad2[node];

    float mx = NEG_INF;
    for (int i = start + lane; i < end; i += 64) {
        int src = csr_src[i];
        float l = as2[src] + ad;
        l = l > 0.f ? l : SLOPE * l;
        mx = fmaxf(mx, l);
    }
    #pragma unroll
    for (int off = 32; off >= 1; off >>= 1) mx = fmaxf(mx, __shfl_xor(mx, off, 64));

    float accA[4] = {0,0,0,0}, accB[4] = {0,0,0,0}, accC[4] = {0,0,0,0}, accD[4] = {0,0,0,0};
    float sumA = 0.f, sumB = 0.f, sumC = 0.f, sumD = 0.f;
    const size_t lo4 = lane * 4;
    int i = start;
    for (; i + 3 < end; i += 4) {
        int s0 = csr_src[i], s1 = csr_src[i+1], s2 = csr_src[i+2], s3 = csr_src[i+3];
        float l0 = as2[s0] + ad, l1 = as2[s1] + ad, l2 = as2[s2] + ad, l3 = as2[s3] + ad;
        uint2 v0 = *(const uint2*)(h2 + (size_t)s0 * D_OUT + lo4);
        uint2 v1 = *(const uint2*)(h2 + (size_t)s1 * D_OUT + lo4);
        uint2 v2 = *(const uint2*)(h2 + (size_t)s2 * D_OUT + lo4);
        uint2 v3 = *(const uint2*)(h2 + (size_t)s3 * D_OUT + lo4);
        l0 = l0 > 0.f ? l0 : SLOPE * l0;  l1 = l1 > 0.f ? l1 : SLOPE * l1;
        l2 = l2 > 0.f ? l2 : SLOPE * l2;  l3 = l3 > 0.f ? l3 : SLOPE * l3;
        float e0 = __expf(l0 - mx), e1 = __expf(l1 - mx), e2 = __expf(l2 - mx), e3 = __expf(l3 - mx);
        sumA += e0; sumB += e1; sumC += e2; sumD += e3;
        accA[0] += bfu_lo(v0.x) * e0; accA[1] += bfu_hi(v0.x) * e0; accA[2] += bfu_lo(v0.y) * e0; accA[3] += bfu_hi(v0.y) * e0;
        accB[0] += bfu_lo(v1.x) * e1; accB[1] += bfu_hi(v1.x) * e1; accB[2] += bfu_lo(v1.y) * e1; accB[3] += bfu_hi(v1.y) * e1;
        accC[0] += bfu_lo(v2.x) * e2; accC[1] += bfu_hi(v2.x) * e2; accC[2] += bfu_lo(v2.y) * e2; accC[3] += bfu_hi(v2.y) * e2;
        accD[0] += bfu_lo(v3.x) * e3; accD[1] += bfu_hi(v3.x) * e3; accD[2] += bfu_lo(v3.y) * e3; accD[3] += bfu_hi(v3.y) * e3;
    }
    for (; i < end; i++) {
        int s0 = csr_src[i];
        float l0 = as2[s0] + ad;
        uint2 v0 = *(const uint2*)(h2 + (size_t)s0 * D_OUT + lo4);
        l0 = l0 > 0.f ? l0 : SLOPE * l0;
        float e0 = __expf(l0 - mx);
        sumA += e0;
        accA[0] += bfu_lo(v0.x) * e0; accA[1] += bfu_hi(v0.x) * e0; accA[2] += bfu_lo(v0.y) * e0; accA[3] += bfu_hi(v0.y) * e0;
    }
    float s = (sumA + sumB) + (sumC + sumD);
    float inv = 1.f / s;
    float4 r;
    r.x = (accA[0] + accB[0] + accC[0] + accD[0]) * inv + b2[lo4 + 0];
    r.y = (accA[1] + accB[1] + accC[1] + accD[1]) * inv + b2[lo4 + 1];
    r.z = (accA[2] + accB[2] + accC[2] + accD[2]) * inv + b2[lo4 + 2];
    r.w = (accA[3] + accB[3] + accC[3] + accD[3]) * inv + b2[lo4 + 3];
    *(float4*)&out[(size_t)node * D_OUT + lo4] = r;
}

// ---------------- launch ----------------

extern "C" void kernel_launch(void* const* d_in, const int* in_sizes, int n_in,
                              void* d_out, int out_size, void* d_ws, size_t ws_size,
                              hipStream_t stream) {
    const float* x   = (const float*)d_in[0];
    const int*   ei  = (const int*)d_in[1];
    const float* W1  = (const float*)d_in[2];
    const float* a1s = (const float*)d_in[3];
    const float* a1d = (const float*)d_in[4];
    const float* b1  = (const float*)d_in[5];
    const float* W2  = (const float*)d_in[6];
    const float* a2s = (const float*)d_in[7];
    const float* a2d = (const float*)d_in[8];
    const float* b2  = (const float*)d_in[9];
    float* out = (float*)d_out;

    char* ws = (char*)d_ws;
    size_t off = 0;
    auto take = [&](size_t bytes) {
        char* p = ws + off;
        off += (bytes + 255) & ~(size_t)255;
        return p;
    };
    int*    deg       = (int*)take(sizeof(int) * N_NODES);
    int*    row_start = (int*)take(sizeof(int) * (N_NODES + 1));
    int*    cursor    = (int*)take(sizeof(int) * N_NODES);
    int*    csr_src   = (int*)take(sizeof(int) * E_TOT);
    ushort* xhi       = (ushort*)take(sizeof(ushort) * (size_t)N_NODES * D_IN);
    ushort* xlo       = (ushort*)take(sizeof(ushort) * (size_t)N_NODES * D_IN);
    ushort* w1h       = (ushort*)take(sizeof(ushort) * D_IN * F1);
    ushort* w1l       = (ushort*)take(sizeof(ushort) * D_IN * F1);
    ushort* w2h       = (ushort*)take(sizeof(ushort) * F1 * D_OUT);
    ushort* w2l       = (ushort*)take(sizeof(ushort) * F1 * D_OUT);
    ushort* h1        = (ushort*)take(sizeof(ushort) * (size_t)N_NODES * F1);
    float*  as1       = (float*)take(sizeof(float) * N_NODES * 4);
    float*  ad1       = (float*)take(sizeof(float) * N_NODES * 4);
    ushort* heluh     = (ushort*)take(sizeof(ushort) * (size_t)N_NODES * F1);
    ushort* helul     = (ushort*)take(sizeof(ushort) * (size_t)N_NODES * F1);
    ushort* h2        = (ushort*)take(sizeof(ushort) * (size_t)N_NODES * D_OUT);
    float*  as2       = (float*)take(sizeof(float) * N_NODES);
    float*  ad2       = (float*)take(sizeof(float) * N_NODES);

    hipMemsetAsync(deg, 0, sizeof(int) * N_NODES, stream);

    int eblocks = (E_TOT + 255) / 256;
    k_hist<<<eblocks, 256, 0, stream>>>(ei, deg);
    k_scan<<<1, 256, 0, stream>>>(deg, row_start, cursor);
    k_scatter<<<eblocks, 256, 0, stream>>>(ei, cursor, csr_src);

    // splits
    int nx = N_NODES * D_IN;
    k_split<<<(nx + 255) / 256, 256, 0, stream>>>(x, xhi, xlo, nx);
    k_splitT<<<(D_IN * F1 + 255) / 256, 256, 0, stream>>>(W1, w1h, w1l, D_IN, F1);
    k_splitT<<<(F1 * D_OUT + 255) / 256, 256, 0, stream>>>(W2, w2h, w2l, F1, D_OUT);

    // layer 1
    k_gemm_mfma<true><<<dim3(F1 / 64, (N_NODES + 127) / 128), 256, 0, stream>>>(
        xhi, xlo, w1h, w1l, (void*)h1, N_NODES, F1, D_IN);
    k_attn_vec1<<<N_NODES, 256, 0, stream>>>(h1, a1s, a1d, as1, ad1);
    k_edge1<<<N_NODES / 4, 256, 0, stream>>>(row_start, csr_src, h1, as1, ad1, b1, heluh, helul);

    // layer 2
    k_gemm_mfma<true><<<dim3(D_OUT / 64, (N_NODES + 127) / 128), 256, 0, stream>>>(
        heluh, helul, w2h, w2l, (void*)h2, N_NODES, D_OUT, F1);
    k_attn_vec2<<<N_NODES / 4, 256, 0, stream>>>(h2, a2s, a2d, as2, ad2);
    k_edge2<<<N_NODES / 4, 256, 0, stream>>>(row_start, csr_src, h2, as2, ad2, b2, out);
}

// Round 4
// 175.284 us; speedup vs baseline: 1.8492x; 1.3084x over previous
//
#include <hip/hip_runtime.h>

#define N_NODES 10000
#define E_RAW   320000
#define E_TOT   330000
#define D_IN    256
#define HID     128
#define HEADS   4
#define F1      512   // HEADS*HID
#define D_OUT   256
#define SLOPE   0.2f

typedef __attribute__((ext_vector_type(8))) short bf16x8;
typedef __attribute__((ext_vector_type(4))) float f32x4;

__device__ __forceinline__ float bf2f(ushort u) {
    return __uint_as_float(((uint)u) << 16);
}
__device__ __forceinline__ ushort f2bf(float x) {
    uint u = __float_as_uint(x);
    uint r = (u + 0x7FFFu + ((u >> 16) & 1u)) >> 16;
    return (ushort)r;
}
__device__ __forceinline__ float bfu_lo(uint u) { return __uint_as_float(u << 16); }
__device__ __forceinline__ float bfu_hi(uint u) { return __uint_as_float(u & 0xFFFF0000u); }

// ---------------- CSR build ----------------

__global__ __launch_bounds__(256) void k_hist(const int* __restrict__ ei, int* __restrict__ deg) {
    int e = blockIdx.x * 256 + threadIdx.x;
    if (e < E_TOT) {
        int dst = (e < E_RAW) ? ei[E_RAW + e] : (e - E_RAW);
        atomicAdd(&deg[dst], 1);
    }
}

#define SCAN_CHUNK 40   // 256*40 = 10240 >= N_NODES

__global__ __launch_bounds__(256) void k_scan(const int* __restrict__ deg,
                                              int* __restrict__ row_start,
                                              int* __restrict__ cursor) {
    __shared__ int tots[256];
    int tid = threadIdx.x;
    int base = tid * SCAN_CHUNK;
    int loc[SCAN_CHUNK];
    int s = 0;
    #pragma unroll
    for (int k = 0; k < SCAN_CHUNK; k++) {
        int idx = base + k;
        int v = (idx < N_NODES) ? deg[idx] : 0;
        loc[k] = s;
        s += v;
    }
    tots[tid] = s;
    __syncthreads();
    for (int off = 1; off < 256; off <<= 1) {
        int t = (tid >= off) ? tots[tid - off] : 0;
        __syncthreads();
        tots[tid] += t;
        __syncthreads();
    }
    int excl = tots[tid] - s;
    #pragma unroll
    for (int k = 0; k < SCAN_CHUNK; k++) {
        int idx = base + k;
        if (idx < N_NODES) {
            int r = excl + loc[k];
            row_start[idx] = r;
            cursor[idx]    = r;
        }
    }
    if (tid == 255) row_start[N_NODES] = E_TOT;
}

__global__ __launch_bounds__(256) void k_scatter(const int* __restrict__ ei,
                                                 int* __restrict__ cursor,
                                                 int* __restrict__ csr_src) {
    int e = blockIdx.x * 256 + threadIdx.x;
    if (e < E_TOT) {
        int src = (e < E_RAW) ? ei[e] : (e - E_RAW);
        int dst = (e < E_RAW) ? ei[E_RAW + e] : (e - E_RAW);
        int pos = atomicAdd(&cursor[dst], 1);
        csr_src[pos] = src;
    }
}

// ---------------- weight transpose + bf16 cast ----------------
// in [K][N] f32 -> out [N][K] bf16

__global__ __launch_bounds__(256) void k_castT(const float* __restrict__ in,
                                               ushort* __restrict__ outp,
                                               int K, int N) {
    int i = blockIdx.x * 256 + threadIdx.x;
    if (i < K * N) {
        int k = i / N, n = i - k * N;
        outp[(size_t)n * K + k] = f2bf(in[i]);
    }
}

// ---------------- MFMA bf16 GEMM ----------------
// C[M,N] = A[M,K] @ B[K,N]; A either f32 [M][K] (cast in staging) or bf16 [M][K];
// B bf16 [N][K] pre-transposed. BM=128 BN=64 BK=64, 4 waves (2x2), 16x16x32 MFMA.

template<bool A_F32>
__global__ __launch_bounds__(256) void k_gemm_mfma(const void* __restrict__ Av,
                                                   const ushort* __restrict__ Bh,
                                                   ushort* __restrict__ C,
                                                   int M, int N, int K) {
    __shared__ ushort sA[128][72];
    __shared__ ushort sB[64][72];

    const int tid = threadIdx.x;
    const int lane = tid & 63;
    const int wid = tid >> 6;
    const int wr = wid >> 1;
    const int wc = wid & 1;
    const int m0 = blockIdx.y * 128;
    const int n0 = blockIdx.x * 64;
    const int fr = lane & 15;
    const int fk = (lane >> 4) * 8;

    f32x4 acc[4][2];
    #pragma unroll
    for (int i = 0; i < 4; i++)
        #pragma unroll
        for (int j = 0; j < 2; j++) acc[i][j] = (f32x4){0.f, 0.f, 0.f, 0.f};

    for (int k0 = 0; k0 < K; k0 += 64) {
        if (A_F32) {
            const float* A = (const float*)Av;
            #pragma unroll
            for (int t = 0; t < 8; t++) {
                int c = tid + 256 * t;            // 0..2047
                int row = c >> 4, kc = (c & 15) << 2;
                int gr = m0 + row;
                gr = gr < M ? gr : M - 1;
                float4 av = *(const float4*)&A[(size_t)gr * K + k0 + kc];
                ushort4 u;
                u.x = f2bf(av.x); u.y = f2bf(av.y); u.z = f2bf(av.z); u.w = f2bf(av.w);
                *(ushort4*)&sA[row][kc] = u;
            }
        } else {
            const ushort* A = (const ushort*)Av;
            #pragma unroll
            for (int t = 0; t < 4; t++) {
                int c = tid + 256 * t;            // 0..1023
                int row = c >> 3, kc = (c & 7) << 3;
                int gr = m0 + row;
                gr = gr < M ? gr : M - 1;
                *(float4*)&sA[row][kc] = *(const float4*)&A[(size_t)gr * K + k0 + kc];
            }
        }
        #pragma unroll
        for (int t = 0; t < 2; t++) {
            int c = tid + 256 * t;
            int col = c >> 3, kc = (c & 7) << 3;
            size_t go = (size_t)(n0 + col) * K + k0 + kc;
            *(float4*)&sB[col][kc] = *(const float4*)&Bh[go];
        }
        __syncthreads();
        #pragma unroll
        for (int kk = 0; kk < 2; kk++) {
            int kb = kk * 32 + fk;
            bf16x8 a_f[4], b_f[2];
            #pragma unroll
            for (int i = 0; i < 4; i++)
                a_f[i] = *(const bf16x8*)&sA[wr * 64 + i * 16 + fr][kb];
            #pragma unroll
            for (int j = 0; j < 2; j++)
                b_f[j] = *(const bf16x8*)&sB[wc * 32 + j * 16 + fr][kb];
            #pragma unroll
            for (int i = 0; i < 4; i++)
                #pragma unroll
                for (int j = 0; j < 2; j++)
                    acc[i][j] = __builtin_amdgcn_mfma_f32_16x16x32_bf16(a_f[i], b_f[j], acc[i][j], 0, 0, 0);
        }
        __syncthreads();
    }

    // C/D layout: col = lane&15, row = (lane>>4)*4 + q
    #pragma unroll
    for (int i = 0; i < 4; i++) {
        #pragma unroll
        for (int j = 0; j < 2; j++) {
            int row_base = m0 + wr * 64 + i * 16 + ((lane >> 4) << 2);
            int col = n0 + wc * 32 + j * 16 + (lane & 15);
            #pragma unroll
            for (int q = 0; q < 4; q++) {
                int r = row_base + q;
                if (r < M) C[(size_t)r * N + col] = f2bf(acc[i][j][q]);
            }
        }
    }
}

// ---------------- attention vectors ----------------

__global__ __launch_bounds__(256) void k_attn_vec1(const ushort* __restrict__ h1,
                                                   const float* __restrict__ a1s,
                                                   const float* __restrict__ a1d,
                                                   float* __restrict__ as1,
                                                   float* __restrict__ ad1) {
    int node = blockIdx.x;
    int tid = threadIdx.x;
    int wave = tid >> 6;   // head
    int lane = tid & 63;
    const ushort* hr = h1 + (size_t)node * F1 + wave * HID;
    const float* svp = a1s + wave * HID;
    const float* dvp = a1d + wave * HID;
    float h0 = bf2f(hr[lane]), h1v = bf2f(hr[lane + 64]);
    float s_ = h0 * svp[lane] + h1v * svp[lane + 64];
    float d_ = h0 * dvp[lane] + h1v * dvp[lane + 64];
    #pragma unroll
    for (int off = 32; off >= 1; off >>= 1) {
        s_ += __shfl_xor(s_, off, 64);
        d_ += __shfl_xor(d_, off, 64);
    }
    if (lane == 0) {
        as1[node * 4 + wave] = s_;
        ad1[node * 4 + wave] = d_;
    }
}

__global__ __launch_bounds__(256) void k_attn_vec2(const ushort* __restrict__ h2,
                                                   const float* __restrict__ a2s,
                                                   const float* __restrict__ a2d,
                                                   float* __restrict__ as2,
                                                   float* __restrict__ ad2) {
    int node = blockIdx.x * 4 + (threadIdx.x >> 6);
    int lane = threadIdx.x & 63;
    uint2 hv = *(const uint2*)(h2 + (size_t)node * D_OUT + lane * 4);
    float h0 = bfu_lo(hv.x), h1v = bfu_hi(hv.x), h2v = bfu_lo(hv.y), h3 = bfu_hi(hv.y);
    float4 sv = *(const float4*)(a2s + lane * 4);
    float4 dv = *(const float4*)(a2d + lane * 4);
    float s_ = h0 * sv.x + h1v * sv.y + h2v * sv.z + h3 * sv.w;
    float d_ = h0 * dv.x + h1v * dv.y + h2v * dv.z + h3 * dv.w;
    #pragma unroll
    for (int off = 32; off >= 1; off >>= 1) {
        s_ += __shfl_xor(s_, off, 64);
        d_ += __shfl_xor(d_, off, 64);
    }
    if (lane == 0) { as2[node] = s_; ad2[node] = d_; }
}

// ---------------- edge aggregation (one wave per node, no max pass) ----------------

__device__ __forceinline__ void fma8(uint4 v, float e, float* acc) {
    acc[0] += bfu_lo(v.x) * e; acc[1] += bfu_hi(v.x) * e;
    acc[2] += bfu_lo(v.y) * e; acc[3] += bfu_hi(v.y) * e;
    acc[4] += bfu_lo(v.z) * e; acc[5] += bfu_hi(v.z) * e;
    acc[6] += bfu_lo(v.w) * e; acc[7] += bfu_hi(v.w) * e;
}

// layer 1: 4 heads x 128 feats; lane covers feats lane*8..+7 (head = lane>>4)
__global__ __launch_bounds__(256) void k_edge1(const int* __restrict__ row_start,
                                               const int* __restrict__ csr_src,
                                               const ushort* __restrict__ h1,
                                               const float* __restrict__ as1,
                                               const float* __restrict__ ad1,
                                               const float* __restrict__ b1,
                                               ushort* __restrict__ heluh) {
    int node = blockIdx.x * 4 + (threadIdx.x >> 6);
    int lane = threadIdx.x & 63;
    int start = row_start[node];
    int end   = row_start[node + 1];
    int h_lane = lane >> 4;

    float adl = ad1[node * 4 + h_lane];

    float acc[8] = {0,0,0,0,0,0,0,0};
    float sum = 0.f;
    const size_t lo8 = (size_t)lane * 8;

    int i = start;
    for (; i + 8 <= end; i += 8) {
        int s[8];
        #pragma unroll
        for (int k = 0; k < 8; k++) s[k] = csr_src[i + k];
        float l[8];
        #pragma unroll
        for (int k = 0; k < 8; k++) l[k] = as1[s[k] * 4 + h_lane];
        uint4 v[8];
        #pragma unroll
        for (int k = 0; k < 8; k++) v[k] = *(const uint4*)(h1 + (size_t)s[k] * F1 + lo8);
        #pragma unroll
        for (int k = 0; k < 8; k++) {
            float t = l[k] + adl;
            t = t > 0.f ? t : SLOPE * t;
            float e = __expf(t);
            sum += e;
            fma8(v[k], e, acc);
        }
    }
    for (; i < end; i++) {
        int s0 = csr_src[i];
        float t = as1[s0 * 4 + h_lane] + adl;
        uint4 v0 = *(const uint4*)(h1 + (size_t)s0 * F1 + lo8);
        t = t > 0.f ? t : SLOPE * t;
        float e = __expf(t);
        sum += e;
        fma8(v0, e, acc);
    }
    float inv = 1.f / sum;

    size_t o = (size_t)node * F1 + lo8;
    const float* bp = b1 + lo8;
    uint pk[4];
    #pragma unroll
    for (int j = 0; j < 4; j++) {
        float v0 = acc[2*j]   * inv + bp[2*j];
        float v1 = acc[2*j+1] * inv + bp[2*j+1];
        v0 = v0 > 0.f ? v0 : (__expf(v0) - 1.f);
        v1 = v1 > 0.f ? v1 : (__expf(v1) - 1.f);
        pk[j] = (uint)f2bf(v0) | ((uint)f2bf(v1) << 16);
    }
    *(uint4*)&heluh[o] = make_uint4(pk[0], pk[1], pk[2], pk[3]);
}

// layer 2: single head, 256 feats bf16; lane covers feats lane*4..+3
__global__ __launch_bounds__(256) void k_edge2(const int* __restrict__ row_start,
                                               const int* __restrict__ csr_src,
                                               const ushort* __restrict__ h2,
                                               const float* __restrict__ as2,
                                               const float* __restrict__ ad2,
                                               const float* __restrict__ b2,
                                               float* __restrict__ out) {
    int node = blockIdx.x * 4 + (threadIdx.x >> 6);
    int lane = threadIdx.x & 63;
    int start = row_start[node];
    int end   = row_start[node + 1];

    float ad = ad2[node];

    float acc[4] = {0,0,0,0};
    float sum = 0.f;
    const size_t lo4 = (size_t)lane * 4;

    int i = start;
    for (; i + 8 <= end; i += 8) {
        int s[8];
        #pragma unroll
        for (int k = 0; k < 8; k++) s[k] = csr_src[i + k];
        float l[8];
        #pragma unroll
        for (int k = 0; k < 8; k++) l[k] = as2[s[k]];
        uint2 v[8];
        #pragma unroll
        for (int k = 0; k < 8; k++) v[k] = *(const uint2*)(h2 + (size_t)s[k] * D_OUT + lo4);
        #pragma unroll
        for (int k = 0; k < 8; k++) {
            float t = l[k] + ad;
            t = t > 0.f ? t : SLOPE * t;
            float e = __expf(t);
            sum += e;
            acc[0] += bfu_lo(v[k].x) * e; acc[1] += bfu_hi(v[k].x) * e;
            acc[2] += bfu_lo(v[k].y) * e; acc[3] += bfu_hi(v[k].y) * e;
        }
    }
    for (; i < end; i++) {
        int s0 = csr_src[i];
        float t = as2[s0] + ad;
        uint2 v0 = *(const uint2*)(h2 + (size_t)s0 * D_OUT + lo4);
        t = t > 0.f ? t : SLOPE * t;
        float e = __expf(t);
        sum += e;
        acc[0] += bfu_lo(v0.x) * e; acc[1] += bfu_hi(v0.x) * e;
        acc[2] += bfu_lo(v0.y) * e; acc[3] += bfu_hi(v0.y) * e;
    }
    float inv = 1.f / sum;
    float4 r;
    r.x = acc[0] * inv + b2[lo4 + 0];
    r.y = acc[1] * inv + b2[lo4 + 1];
    r.z = acc[2] * inv + b2[lo4 + 2];
    r.w = acc[3] * inv + b2[lo4 + 3];
    *(float4*)&out[(size_t)node * D_OUT + lo4] = r;
}

// ---------------- launch ----------------

extern "C" void kernel_launch(void* const* d_in, const int* in_sizes, int n_in,
                              void* d_out, int out_size, void* d_ws, size_t ws_size,
                              hipStream_t stream) {
    const float* x   = (const float*)d_in[0];
    const int*   ei  = (const int*)d_in[1];
    const float* W1  = (const float*)d_in[2];
    const float* a1s = (const float*)d_in[3];
    const float* a1d = (const float*)d_in[4];
    const float* b1  = (const float*)d_in[5];
    const float* W2  = (const float*)d_in[6];
    const float* a2s = (const float*)d_in[7];
    const float* a2d = (const float*)d_in[8];
    const float* b2  = (const float*)d_in[9];
    float* out = (float*)d_out;

    char* ws = (char*)d_ws;
    size_t off = 0;
    auto take = [&](size_t bytes) {
        char* p = ws + off;
        off += (bytes + 255) & ~(size_t)255;
        return p;
    };
    int*    deg       = (int*)take(sizeof(int) * N_NODES);
    int*    row_start = (int*)take(sizeof(int) * (N_NODES + 1));
    int*    cursor    = (int*)take(sizeof(int) * N_NODES);
    int*    csr_src   = (int*)take(sizeof(int) * E_TOT);
    ushort* w1h       = (ushort*)take(sizeof(ushort) * D_IN * F1);
    ushort* w2h       = (ushort*)take(sizeof(ushort) * F1 * D_OUT);
    ushort* h1        = (ushort*)take(sizeof(ushort) * (size_t)N_NODES * F1);
    float*  as1       = (float*)take(sizeof(float) * N_NODES * 4);
    float*  ad1       = (float*)take(sizeof(float) * N_NODES * 4);
    ushort* heluh     = (ushort*)take(sizeof(ushort) * (size_t)N_NODES * F1);
    ushort* h2        = (ushort*)take(sizeof(ushort) * (size_t)N_NODES * D_OUT);
    float*  as2       = (float*)take(sizeof(float) * N_NODES);
    float*  ad2       = (float*)take(sizeof(float) * N_NODES);

    hipMemsetAsync(deg, 0, sizeof(int) * N_NODES, stream);

    int eblocks = (E_TOT + 255) / 256;
    k_hist<<<eblocks, 256, 0, stream>>>(ei, deg);
    k_scan<<<1, 256, 0, stream>>>(deg, row_start, cursor);
    k_scatter<<<eblocks, 256, 0, stream>>>(ei, cursor, csr_src);

    // weight transpose + cast
    k_castT<<<(D_IN * F1 + 255) / 256, 256, 0, stream>>>(W1, w1h, D_IN, F1);
    k_castT<<<(F1 * D_OUT + 255) / 256, 256, 0, stream>>>(W2, w2h, F1, D_OUT);

    // layer 1
    k_gemm_mfma<true><<<dim3(F1 / 64, (N_NODES + 127) / 128), 256, 0, stream>>>(
        (const void*)x, w1h, h1, N_NODES, F1, D_IN);
    k_attn_vec1<<<N_NODES, 256, 0, stream>>>(h1, a1s, a1d, as1, ad1);
    k_edge1<<<N_NODES / 4, 256, 0, stream>>>(row_start, csr_src, h1, as1, ad1, b1, heluh);

    // layer 2
    k_gemm_mfma<false><<<dim3(D_OUT / 64, (N_NODES + 127) / 128), 256, 0, stream>>>(
        (const void*)heluh, w2h, h2, N_NODES, D_OUT, F1);
    k_attn_vec2<<<N_NODES / 4, 256, 0, stream>>>(h2, a2s, a2d, as2, ad2);
    k_edge2<<<N_NODES / 4, 256, 0, stream>>>(row_start, csr_src, h2, as2, ad2, b2, out);
}

// Round 5
// 168.076 us; speedup vs baseline: 1.9285x; 1.0429x over previous
//
#include <hip/hip_runtime.h>

#define N_NODES 10000
#define E_RAW   320000
#define E_TOT   330000
#define D_IN    256
#define HID     128
#define HEADS   4
#define F1      512   // HEADS*HID
#define D_OUT   256
#define SLOPE   0.2f

typedef __attribute__((ext_vector_type(8))) short bf16x8;
typedef __attribute__((ext_vector_type(4))) float f32x4;

__device__ __forceinline__ float bf2f(ushort u) {
    return __uint_as_float(((uint)u) << 16);
}
__device__ __forceinline__ ushort f2bf(float x) {
    uint u = __float_as_uint(x);
    uint r = (u + 0x7FFFu + ((u >> 16) & 1u)) >> 16;
    return (ushort)r;
}
__device__ __forceinline__ float bfu_lo(uint u) { return __uint_as_float(u << 16); }
__device__ __forceinline__ float bfu_hi(uint u) { return __uint_as_float(u & 0xFFFF0000u); }

// async global->LDS, 16B per lane; dest must be wave-uniform base (+lane*16 implicit)
__device__ __forceinline__ void gload_lds16(const void* g, void* l) {
    __builtin_amdgcn_global_load_lds(
        (const __attribute__((address_space(1))) void*)g,
        (__attribute__((address_space(3))) void*)l, 16, 0, 0);
}

// ---------------- CSR build ----------------

__global__ __launch_bounds__(256) void k_zero(int* __restrict__ p, int n) {
    int i = blockIdx.x * 256 + threadIdx.x;
    if (i < n) p[i] = 0;
}

__global__ __launch_bounds__(256) void k_hist(const int* __restrict__ ei, int* __restrict__ deg) {
    int e = blockIdx.x * 256 + threadIdx.x;
    if (e < E_TOT) {
        int dst = (e < E_RAW) ? ei[E_RAW + e] : (e - E_RAW);
        atomicAdd(&deg[dst], 1);
    }
}

#define SCAN_CHUNK 40   // 256*40 = 10240 >= N_NODES

__global__ __launch_bounds__(256) void k_scan(const int* __restrict__ deg,
                                              int* __restrict__ row_start,
                                              int* __restrict__ cursor) {
    __shared__ int tots[256];
    int tid = threadIdx.x;
    int base = tid * SCAN_CHUNK;
    int loc[SCAN_CHUNK];
    int s = 0;
    #pragma unroll
    for (int k = 0; k < SCAN_CHUNK; k++) {
        int idx = base + k;
        int v = (idx < N_NODES) ? deg[idx] : 0;
        loc[k] = s;
        s += v;
    }
    tots[tid] = s;
    __syncthreads();
    for (int off = 1; off < 256; off <<= 1) {
        int t = (tid >= off) ? tots[tid - off] : 0;
        __syncthreads();
        tots[tid] += t;
        __syncthreads();
    }
    int excl = tots[tid] - s;
    #pragma unroll
    for (int k = 0; k < SCAN_CHUNK; k++) {
        int idx = base + k;
        if (idx < N_NODES) {
            int r = excl + loc[k];
            row_start[idx] = r;
            cursor[idx]    = r;
        }
    }
    if (tid == 255) row_start[N_NODES] = E_TOT;
}

__global__ __launch_bounds__(256) void k_scatter(const int* __restrict__ ei,
                                                 int* __restrict__ cursor,
                                                 int* __restrict__ csr_src) {
    int e = blockIdx.x * 256 + threadIdx.x;
    if (e < E_TOT) {
        int src = (e < E_RAW) ? ei[e] : (e - E_RAW);
        int dst = (e < E_RAW) ? ei[E_RAW + e] : (e - E_RAW);
        int pos = atomicAdd(&cursor[dst], 1);
        csr_src[pos] = src;
    }
}

// ---------------- casts ----------------

// flat f32 -> bf16, 8 elems/thread
__global__ __launch_bounds__(256) void k_cast8(const float* __restrict__ in,
                                               ushort* __restrict__ outp, int n8) {
    int i = blockIdx.x * 256 + threadIdx.x;
    if (i < n8) {
        float4 a = *(const float4*)&in[(size_t)i * 8];
        float4 b = *(const float4*)&in[(size_t)i * 8 + 4];
        uint4 u;
        u.x = (uint)f2bf(a.x) | ((uint)f2bf(a.y) << 16);
        u.y = (uint)f2bf(a.z) | ((uint)f2bf(a.w) << 16);
        u.z = (uint)f2bf(b.x) | ((uint)f2bf(b.y) << 16);
        u.w = (uint)f2bf(b.z) | ((uint)f2bf(b.w) << 16);
        *(uint4*)&outp[(size_t)i * 8] = u;
    }
}

// in [K][N] f32 -> out [N][K] bf16 (weight transpose)
__global__ __launch_bounds__(256) void k_castT(const float* __restrict__ in,
                                               ushort* __restrict__ outp,
                                               int K, int N) {
    int i = blockIdx.x * 256 + threadIdx.x;
    if (i < K * N) {
        int k = i / N, n = i - k * N;
        outp[(size_t)n * K + k] = f2bf(in[i]);
    }
}

// ---------------- MFMA bf16 GEMM (global_load_lds + XOR swizzle) ----------------
// C[M,N] = A[M,K] @ B[K,N]; A bf16 [M][K], B bf16 [N][K] pre-transposed.
// BM=128 BN=64 BK=64, 4 waves (2x2), 16x16x32 MFMA.
// LDS linear rows of 64 bf16 (128B); 16B slot s at row r holds logical slot s^(r&7).

__global__ __launch_bounds__(256) void k_gemm(const ushort* __restrict__ A,
                                              const ushort* __restrict__ B,
                                              ushort* __restrict__ C,
                                              int M, int N, int K) {
    __shared__ ushort sA[128 * 64];
    __shared__ ushort sB[64 * 64];

    const int tid = threadIdx.x;
    const int lane = tid & 63;
    const int wid = tid >> 6;
    const int wr = wid >> 1;
    const int wc = wid & 1;
    const int m0 = blockIdx.y * 128;
    const int n0 = blockIdx.x * 64;
    const int fr = lane & 15;
    const int fs = lane >> 4;          // k-slot group 0..3

    // staging geometry: lane covers 16B slot (l&7) of row (l>>3) within an 8-row chunk
    const int rowc = lane >> 3;
    const int slot = (lane & 7) ^ rowc;   // inverse-swizzled global 16B slot

    f32x4 acc[4][2];
    #pragma unroll
    for (int i = 0; i < 4; i++)
        #pragma unroll
        for (int j = 0; j < 2; j++) acc[i][j] = (f32x4){0.f, 0.f, 0.f, 0.f};

    for (int k0 = 0; k0 < K; k0 += 64) {
        // A tile: 16 chunks x (8 rows x 128B); wave handles 4 chunks
        #pragma unroll
        for (int t = 0; t < 4; t++) {
            int c = wid + 4 * t;
            int gr = m0 + c * 8 + rowc;
            gr = gr < M ? gr : M - 1;
            gload_lds16(A + (size_t)gr * K + k0 + slot * 8, &sA[c * 512]);
        }
        // B tile: 8 chunks; wave handles 2
        #pragma unroll
        for (int t = 0; t < 2; t++) {
            int c = wid + 4 * t;
            int gc = n0 + c * 8 + rowc;
            gload_lds16(B + (size_t)gc * K + k0 + slot * 8, &sB[c * 512]);
        }
        __syncthreads();
        #pragma unroll
        for (int kk = 0; kk < 2; kk++) {
            int sbase = kk * 4 + fs;   // logical 16B slot within row
            bf16x8 a_f[4], b_f[2];
            #pragma unroll
            for (int i = 0; i < 4; i++) {
                int r = wr * 64 + i * 16 + fr;
                a_f[i] = *(const bf16x8*)&sA[r * 64 + ((sbase ^ (r & 7)) << 3)];
            }
            #pragma unroll
            for (int j = 0; j < 2; j++) {
                int cc = wc * 32 + j * 16 + fr;
                b_f[j] = *(const bf16x8*)&sB[cc * 64 + ((sbase ^ (cc & 7)) << 3)];
            }
            #pragma unroll
            for (int i = 0; i < 4; i++)
                #pragma unroll
                for (int j = 0; j < 2; j++)
                    acc[i][j] = __builtin_amdgcn_mfma_f32_16x16x32_bf16(a_f[i], b_f[j], acc[i][j], 0, 0, 0);
        }
        __syncthreads();
    }

    // C/D layout: col = lane&15, row = (lane>>4)*4 + q
    #pragma unroll
    for (int i = 0; i < 4; i++) {
        #pragma unroll
        for (int j = 0; j < 2; j++) {
            int row_base = m0 + wr * 64 + i * 16 + ((lane >> 4) << 2);
            int col = n0 + wc * 32 + j * 16 + (lane & 15);
            #pragma unroll
            for (int q = 0; q < 4; q++) {
                int r = row_base + q;
                if (r < M) C[(size_t)r * N + col] = f2bf(acc[i][j][q]);
            }
        }
    }
}

// ---------------- attention vectors ----------------

// layer 1: one wave per node; lane covers feats lane*8..+7, head = lane>>4
__global__ __launch_bounds__(256) void k_attn_vec1(const ushort* __restrict__ h1,
                                                   const float* __restrict__ a1s,
                                                   const float* __restrict__ a1d,
                                                   float* __restrict__ as1,
                                                   float* __restrict__ ad1) {
    int node = blockIdx.x * 4 + (threadIdx.x >> 6);
    int lane = threadIdx.x & 63;
    uint4 hv = *(const uint4*)(h1 + (size_t)node * F1 + (size_t)lane * 8);
    const float* sp = a1s + lane * 8;
    const float* dp = a1d + lane * 8;
    float4 sa = *(const float4*)sp, sb = *(const float4*)(sp + 4);
    float4 da = *(const float4*)dp, db = *(const float4*)(dp + 4);
    float h0 = bfu_lo(hv.x), h1v = bfu_hi(hv.x), h2v = bfu_lo(hv.y), h3 = bfu_hi(hv.y);
    float h4 = bfu_lo(hv.z), h5 = bfu_hi(hv.z), h6 = bfu_lo(hv.w), h7 = bfu_hi(hv.w);
    float s_ = h0*sa.x + h1v*sa.y + h2v*sa.z + h3*sa.w + h4*sb.x + h5*sb.y + h6*sb.z + h7*sb.w;
    float d_ = h0*da.x + h1v*da.y + h2v*da.z + h3*da.w + h4*db.x + h5*db.y + h6*db.z + h7*db.w;
    #pragma unroll
    for (int off = 8; off >= 1; off >>= 1) {
        s_ += __shfl_xor(s_, off, 64);
        d_ += __shfl_xor(d_, off, 64);
    }
    if ((lane & 15) == 0) {
        int head = lane >> 4;
        as1[node * 4 + head] = s_;
        ad1[node * 4 + head] = d_;
    }
}

__global__ __launch_bounds__(256) void k_attn_vec2(const ushort* __restrict__ h2,
                                                   const float* __restrict__ a2s,
                                                   const float* __restrict__ a2d,
                                                   float* __restrict__ as2,
                                                   float* __restrict__ ad2) {
    int node = blockIdx.x * 4 + (threadIdx.x >> 6);
    int lane = threadIdx.x & 63;
    uint2 hv = *(const uint2*)(h2 + (size_t)node * D_OUT + lane * 4);
    float h0 = bfu_lo(hv.x), h1v = bfu_hi(hv.x), h2v = bfu_lo(hv.y), h3 = bfu_hi(hv.y);
    float4 sv = *(const float4*)(a2s + lane * 4);
    float4 dv = *(const float4*)(a2d + lane * 4);
    float s_ = h0 * sv.x + h1v * sv.y + h2v * sv.z + h3 * sv.w;
    float d_ = h0 * dv.x + h1v * dv.y + h2v * dv.z + h3 * dv.w;
    #pragma unroll
    for (int off = 32; off >= 1; off >>= 1) {
        s_ += __shfl_xor(s_, off, 64);
        d_ += __shfl_xor(d_, off, 64);
    }
    if (lane == 0) { as2[node] = s_; ad2[node] = d_; }
}

// ---------------- edge aggregation (one wave per node, no max pass) ----------------

__device__ __forceinline__ void fma8(uint4 v, float e, float* acc) {
    acc[0] += bfu_lo(v.x) * e; acc[1] += bfu_hi(v.x) * e;
    acc[2] += bfu_lo(v.y) * e; acc[3] += bfu_hi(v.y) * e;
    acc[4] += bfu_lo(v.z) * e; acc[5] += bfu_hi(v.z) * e;
    acc[6] += bfu_lo(v.w) * e; acc[7] += bfu_hi(v.w) * e;
}

// layer 1: 4 heads x 128 feats; lane covers feats lane*8..+7 (head = lane>>4)
__global__ __launch_bounds__(256) void k_edge1(const int* __restrict__ row_start,
                                               const int* __restrict__ csr_src,
                                               const ushort* __restrict__ h1,
                                               const float* __restrict__ as1,
                                               const float* __restrict__ ad1,
                                               const float* __restrict__ b1,
                                               ushort* __restrict__ heluh) {
    int node = blockIdx.x * 4 + (threadIdx.x >> 6);
    int lane = threadIdx.x & 63;
    int start = row_start[node];
    int end   = row_start[node + 1];
    int h_lane = lane >> 4;

    float adl = ad1[node * 4 + h_lane];

    float acc[8] = {0,0,0,0,0,0,0,0};
    float sum = 0.f;
    const size_t lo8 = (size_t)lane * 8;

    int i = start;
    for (; i + 8 <= end; i += 8) {
        int s[8];
        #pragma unroll
        for (int k = 0; k < 8; k++) s[k] = csr_src[i + k];
        float l[8];
        #pragma unroll
        for (int k = 0; k < 8; k++) l[k] = as1[s[k] * 4 + h_lane];
        uint4 v[8];
        #pragma unroll
        for (int k = 0; k < 8; k++) v[k] = *(const uint4*)(h1 + (size_t)s[k] * F1 + lo8);
        #pragma unroll
        for (int k = 0; k < 8; k++) {
            float t = l[k] + adl;
            t = t > 0.f ? t : SLOPE * t;
            float e = __expf(t);
            sum += e;
            fma8(v[k], e, acc);
        }
    }
    for (; i < end; i++) {
        int s0 = csr_src[i];
        float t = as1[s0 * 4 + h_lane] + adl;
        uint4 v0 = *(const uint4*)(h1 + (size_t)s0 * F1 + lo8);
        t = t > 0.f ? t : SLOPE * t;
        float e = __expf(t);
        sum += e;
        fma8(v0, e, acc);
    }
    float inv = 1.f / sum;

    size_t o = (size_t)node * F1 + lo8;
    const float* bp = b1 + lo8;
    uint pk[4];
    #pragma unroll
    for (int j = 0; j < 4; j++) {
        float v0 = acc[2*j]   * inv + bp[2*j];
        float v1 = acc[2*j+1] * inv + bp[2*j+1];
        v0 = v0 > 0.f ? v0 : (__expf(v0) - 1.f);
        v1 = v1 > 0.f ? v1 : (__expf(v1) - 1.f);
        pk[j] = (uint)f2bf(v0) | ((uint)f2bf(v1) << 16);
    }
    *(uint4*)&heluh[o] = make_uint4(pk[0], pk[1], pk[2], pk[3]);
}

// layer 2: single head, 256 feats bf16; lane covers feats lane*4..+3
__global__ __launch_bounds__(256) void k_edge2(const int* __restrict__ row_start,
                                               const int* __restrict__ csr_src,
                                               const ushort* __restrict__ h2,
                                               const float* __restrict__ as2,
                                               const float* __restrict__ ad2,
                                               const float* __restrict__ b2,
                                               float* __restrict__ out) {
    int node = blockIdx.x * 4 + (threadIdx.x >> 6);
    int lane = threadIdx.x & 63;
    int start = row_start[node];
    int end   = row_start[node + 1];

    float ad = ad2[node];

    float acc[4] = {0,0,0,0};
    float sum = 0.f;
    const size_t lo4 = (size_t)lane * 4;

    int i = start;
    for (; i + 8 <= end; i += 8) {
        int s[8];
        #pragma unroll
        for (int k = 0; k < 8; k++) s[k] = csr_src[i + k];
        float l[8];
        #pragma unroll
        for (int k = 0; k < 8; k++) l[k] = as2[s[k]];
        uint2 v[8];
        #pragma unroll
        for (int k = 0; k < 8; k++) v[k] = *(const uint2*)(h2 + (size_t)s[k] * D_OUT + lo4);
        #pragma unroll
        for (int k = 0; k < 8; k++) {
            float t = l[k] + ad;
            t = t > 0.f ? t : SLOPE * t;
            float e = __expf(t);
            sum += e;
            acc[0] += bfu_lo(v[k].x) * e; acc[1] += bfu_hi(v[k].x) * e;
            acc[2] += bfu_lo(v[k].y) * e; acc[3] += bfu_hi(v[k].y) * e;
        }
    }
    for (; i < end; i++) {
        int s0 = csr_src[i];
        float t = as2[s0] + ad;
        uint2 v0 = *(const uint2*)(h2 + (size_t)s0 * D_OUT + lo4);
        t = t > 0.f ? t : SLOPE * t;
        float e = __expf(t);
        sum += e;
        acc[0] += bfu_lo(v0.x) * e; acc[1] += bfu_hi(v0.x) * e;
        acc[2] += bfu_lo(v0.y) * e; acc[3] += bfu_hi(v0.y) * e;
    }
    float inv = 1.f / sum;
    float4 r;
    r.x = acc[0] * inv + b2[lo4 + 0];
    r.y = acc[1] * inv + b2[lo4 + 1];
    r.z = acc[2] * inv + b2[lo4 + 2];
    r.w = acc[3] * inv + b2[lo4 + 3];
    *(float4*)&out[(size_t)node * D_OUT + lo4] = r;
}

// ---------------- launch ----------------

extern "C" void kernel_launch(void* const* d_in, const int* in_sizes, int n_in,
                              void* d_out, int out_size, void* d_ws, size_t ws_size,
                              hipStream_t stream) {
    const float* x   = (const float*)d_in[0];
    const int*   ei  = (const int*)d_in[1];
    const float* W1  = (const float*)d_in[2];
    const float* a1s = (const float*)d_in[3];
    const float* a1d = (const float*)d_in[4];
    const float* b1  = (const float*)d_in[5];
    const float* W2  = (const float*)d_in[6];
    const float* a2s = (const float*)d_in[7];
    const float* a2d = (const float*)d_in[8];
    const float* b2  = (const float*)d_in[9];
    float* out = (float*)d_out;

    char* ws = (char*)d_ws;
    size_t off = 0;
    auto take = [&](size_t bytes) {
        char* p = ws + off;
        off += (bytes + 255) & ~(size_t)255;
        return p;
    };
    int*    deg       = (int*)take(sizeof(int) * N_NODES);
    int*    row_start = (int*)take(sizeof(int) * (N_NODES + 1));
    int*    cursor    = (int*)take(sizeof(int) * N_NODES);
    int*    csr_src   = (int*)take(sizeof(int) * E_TOT);
    ushort* xb        = (ushort*)take(sizeof(ushort) * (size_t)N_NODES * D_IN);
    ushort* w1h       = (ushort*)take(sizeof(ushort) * D_IN * F1);
    ushort* w2h       = (ushort*)take(sizeof(ushort) * F1 * D_OUT);
    ushort* h1        = (ushort*)take(sizeof(ushort) * (size_t)N_NODES * F1);
    float*  as1       = (float*)take(sizeof(float) * N_NODES * 4);
    float*  ad1       = (float*)take(sizeof(float) * N_NODES * 4);
    ushort* heluh     = (ushort*)take(sizeof(ushort) * (size_t)N_NODES * F1);
    ushort* h2        = (ushort*)take(sizeof(ushort) * (size_t)N_NODES * D_OUT);
    float*  as2       = (float*)take(sizeof(float) * N_NODES);
    float*  ad2       = (float*)take(sizeof(float) * N_NODES);

    int eblocks = (E_TOT + 255) / 256;
    k_zero<<<(N_NODES + 255) / 256, 256, 0, stream>>>(deg, N_NODES);
    k_hist<<<eblocks, 256, 0, stream>>>(ei, deg);
    k_scan<<<1, 256, 0, stream>>>(deg, row_start, cursor);
    k_scatter<<<eblocks, 256, 0, stream>>>(ei, cursor, csr_src);

    // casts
    k_cast8<<<(N_NODES * D_IN / 8 + 255) / 256, 256, 0, stream>>>(x, xb, N_NODES * D_IN / 8);
    k_castT<<<(D_IN * F1 + 255) / 256, 256, 0, stream>>>(W1, w1h, D_IN, F1);
    k_castT<<<(F1 * D_OUT + 255) / 256, 256, 0, stream>>>(W2, w2h, F1, D_OUT);

    // layer 1
    k_gemm<<<dim3(F1 / 64, (N_NODES + 127) / 128), 256, 0, stream>>>(xb, w1h, h1, N_NODES, F1, D_IN);
    k_attn_vec1<<<N_NODES / 4, 256, 0, stream>>>(h1, a1s, a1d, as1, ad1);
    k_edge1<<<N_NODES / 4, 256, 0, stream>>>(row_start, csr_src, h1, as1, ad1, b1, heluh);

    // layer 2
    k_gemm<<<dim3(D_OUT / 64, (N_NODES + 127) / 128), 256, 0, stream>>>(heluh, w2h, h2, N_NODES, D_OUT, F1);
    k_attn_vec2<<<N_NODES / 4, 256, 0, stream>>>(h2, a2s, a2d, as2, ad2);
    k_edge2<<<N_NODES / 4, 256, 0, stream>>>(row_start, csr_src, h2, as2, ad2, b2, out);
}